// Round 1
// baseline (311.207 us; speedup 1.0000x reference)
//
#include <hip/hip_runtime.h>
#include <hip/hip_bf16.h>

typedef __attribute__((ext_vector_type(8))) short bf16x8;
typedef __attribute__((ext_vector_type(4))) float f32x4;

#define DI __device__ __forceinline__

static constexpr int Bb  = 2;
static constexpr int Tt  = 1024;
static constexpr int Cc  = 2048;
static constexpr int Hh  = 16;
static constexpr int Dd  = 128;
static constexpr int TC  = 1024;   // cached tokens (seq_start)
static constexpr int CTX = 2048;   // total context
static constexpr float QSCALE = 0.08838834764831845f; // 1/sqrt(128)

DI unsigned short f2bf(float f){
  unsigned u = __builtin_bit_cast(unsigned, f);
  u += 0x7FFFu + ((u >> 16) & 1u);
  return (unsigned short)(u >> 16);
}

// ---- transpose fp32 [R][C] -> bf16 [C][R], batched over blockIdx.z ----
__global__ __launch_bounds__(256) void transpose_f32_bf16(
    const float* __restrict__ in, unsigned short* __restrict__ out, int R, int C){
  __shared__ unsigned short tile[32][33];
  size_t boff = (size_t)blockIdx.z * R * C;
  in += boff; out += boff;
  int r0 = blockIdx.y * 32, c0 = blockIdx.x * 32;
  int tx = threadIdx.x & 31, ty = threadIdx.x >> 5;
#pragma unroll
  for(int i=0;i<4;i++){
    int r = r0 + ty + i*8;
    tile[ty + i*8][tx] = f2bf(in[(size_t)r * C + c0 + tx]);
  }
  __syncthreads();
#pragma unroll
  for(int i=0;i<4;i++){
    int c = c0 + ty + i*8;
    out[(size_t)c * R + r0 + tx] = tile[tx][ty + i*8];
  }
}

// ---- copy KV cache into output k/v buffers ----
__global__ __launch_bounds__(256) void cache_copy(
    const float4* __restrict__ ck, const float4* __restrict__ cv,
    float4* __restrict__ ok, float4* __restrict__ ov){
  int idx = blockIdx.x * 256 + threadIdx.x;      // grid sized exactly
  const int per = TC * Dd / 4;                   // 32768 per (b,h)
  int bh = idx / per, r = idx - bh * per;
  int dst = bh * (CTX * Dd / 4) + r;
  ok[dst] = ck[idx];
  ov[dst] = cv[idx];
}

// ---- GEMM: C[m][n] = sum_k A[m][k] * W[k][n], BT = bf16 W^T [N][K] ----
// AMODE 0: A fp32, AMODE 1: A bf16.
// EPI 0: QKV scatter epilogue. EPI 1: bias + fp32 store.
template<int AMODE, int EPI>
__global__ __launch_bounds__(256) void gemm_k(
    const void* __restrict__ Aptr, const unsigned short* __restrict__ BT,
    unsigned short* __restrict__ q_ws, float* __restrict__ out_k,
    float* __restrict__ out_v, const float* __restrict__ bias,
    float* __restrict__ outp){
  constexpr int K = 2048;
  __shared__ unsigned short Al[128*40];   // [row][40] pad -> 80B stride
  __shared__ unsigned short Bl[128*40];
  int tid = threadIdx.x;
  int lane = tid & 63, w = tid >> 6;
  int lr = lane & 15, lg = lane >> 4;
  int m0 = blockIdx.x * 128, n0 = blockIdx.y * 128;
  int wr = (w >> 1) * 64, wc = (w & 1) * 64;

  f32x4 acc[4][4];
#pragma unroll
  for(int i=0;i<4;i++)
#pragma unroll
    for(int j=0;j<4;j++) acc[i][j] = (f32x4){0.f,0.f,0.f,0.f};

  for(int k0 = 0; k0 < K; k0 += 32){
    if constexpr (AMODE == 0){
      const float* A = (const float*)Aptr;
#pragma unroll
      for(int it=0; it<4; it++){
        int idx = it*256 + tid;
        int row = idx >> 3, col = (idx & 7) * 4;
        float4 a4 = *(const float4*)(A + (size_t)(m0+row)*K + k0 + col);
        uint2 p;
        p.x = (unsigned)f2bf(a4.x) | ((unsigned)f2bf(a4.y) << 16);
        p.y = (unsigned)f2bf(a4.z) | ((unsigned)f2bf(a4.w) << 16);
        *(uint2*)&Al[row*40 + col] = p;
      }
    } else {
      const unsigned short* A = (const unsigned short*)Aptr;
#pragma unroll
      for(int it=0; it<2; it++){
        int idx = it*256 + tid;
        int row = idx >> 2, col = (idx & 3) * 8;
        uint4 a = *(const uint4*)(A + (size_t)(m0+row)*K + k0 + col);
        *(uint4*)&Al[row*40 + col] = a;
      }
    }
#pragma unroll
    for(int it=0; it<2; it++){
      int idx = it*256 + tid;
      int row = idx >> 2, col = (idx & 3) * 8;
      uint4 bq = *(const uint4*)(BT + (size_t)(n0+row)*K + k0 + col);
      *(uint4*)&Bl[row*40 + col] = bq;
    }
    __syncthreads();
    bf16x8 af[4], bfr[4];
#pragma unroll
    for(int mi=0;mi<4;mi++) af[mi]  = *(const bf16x8*)&Al[(wr + mi*16 + lr)*40 + lg*8];
#pragma unroll
    for(int ni=0;ni<4;ni++) bfr[ni] = *(const bf16x8*)&Bl[(wc + ni*16 + lr)*40 + lg*8];
#pragma unroll
    for(int mi=0;mi<4;mi++)
#pragma unroll
      for(int ni=0;ni<4;ni++)
        acc[mi][ni] = __builtin_amdgcn_mfma_f32_16x16x32_bf16(af[mi], bfr[ni], acc[mi][ni], 0, 0, 0);
    __syncthreads();
  }

#pragma unroll
  for(int mi=0;mi<4;mi++){
#pragma unroll
    for(int ni=0;ni<4;ni++){
      int n = n0 + wc + ni*16 + lr;
#pragma unroll
      for(int r=0;r<4;r++){
        int m = m0 + wr + mi*16 + lg*4 + r;
        float v = acc[mi][ni][r];
        if constexpr (EPI == 0){
          int seg = n >> 11;          // 0:q 1:k 2:v (uniform per block)
          int h   = (n >> 7) & 15;
          int d   = n & 127;
          int b   = m >> 10, t = m & 1023;
          if(seg == 0){
            q_ws[((size_t)(b*Hh + h)*Tt + t)*Dd + d] = f2bf(v * QSCALE);
          } else if(seg == 1){
            out_k[((size_t)(b*Hh + h)*CTX + TC + t)*Dd + d] = v;
          } else {
            out_v[((size_t)(b*Hh + h)*CTX + TC + t)*Dd + d] = v;
          }
        } else {
          outp[(size_t)m * 2048 + n] = v + bias[n];
        }
      }
    }
  }
}

// ---- flash attention: one block = (b,h,64 q-rows); 4 waves x 16 rows ----
__global__ __launch_bounds__(256) void attn_k(
    const unsigned short* __restrict__ q_ws, const float* __restrict__ Kg,
    const unsigned short* __restrict__ Vt, unsigned short* __restrict__ attn_out){
  __shared__ unsigned short Kl[32*136];   // [key][128+8] bf16
  __shared__ unsigned short Vl[128*40];   // [d][32+8] bf16 (V^T tile)
  __shared__ unsigned short Pl[4*16*40];  // per-wave P tile [16][40]
  int tid = threadIdx.x;
  int lane = tid & 63, w = tid >> 6;
  int lr = lane & 15, lg = lane >> 4;
  int qt = blockIdx.x, h = blockIdx.y, b = blockIdx.z;
  int bh = b * Hh + h;
  int q0 = qt * 64;
  int qw = q0 + w * 16;

  const unsigned short* qp = q_ws + ((size_t)bh * Tt + qw + lr) * Dd;
  bf16x8 qf[4];
#pragma unroll
  for(int kk=0;kk<4;kk++) qf[kk] = *(const bf16x8*)(qp + kk*32 + lg*8);

  f32x4 o[8];
#pragma unroll
  for(int i=0;i<8;i++) o[i] = (f32x4){0.f,0.f,0.f,0.f};
  float mrun[4], lrun[4];
#pragma unroll
  for(int r=0;r<4;r++){ mrun[r] = -3e38f; lrun[r] = 0.f; }

  const float* Kb = Kg + (size_t)bh * CTX * Dd;
  const unsigned short* Vb = Vt + (size_t)bh * Dd * CTX;
  unsigned short* Pw = &Pl[w * 640];

  int ntiles = (TC + q0 + 64) >> 5;
  int nfull  = (TC + q0) >> 5;

  for(int jt = 0; jt < ntiles; jt++){
    int j0 = jt * 32;
#pragma unroll
    for(int it=0; it<4; it++){
      int idx = it*256 + tid;
      int row = idx >> 5, col = (idx & 31) * 4;
      float4 k4 = *(const float4*)(Kb + (size_t)(j0+row)*Dd + col);
      uint2 p;
      p.x = (unsigned)f2bf(k4.x) | ((unsigned)f2bf(k4.y) << 16);
      p.y = (unsigned)f2bf(k4.z) | ((unsigned)f2bf(k4.w) << 16);
      *(uint2*)&Kl[row*136 + col] = p;
    }
#pragma unroll
    for(int it=0; it<2; it++){
      int idx = it*256 + tid;
      int row = idx >> 2, col = (idx & 3) * 8;
      uint4 v = *(const uint4*)(Vb + (size_t)row*CTX + j0 + col);
      *(uint4*)&Vl[row*40 + col] = v;
    }
    __syncthreads();

    f32x4 s0 = (f32x4){0.f,0.f,0.f,0.f};
    f32x4 s1 = (f32x4){0.f,0.f,0.f,0.f};
#pragma unroll
    for(int kk=0;kk<4;kk++){
      bf16x8 k0f = *(const bf16x8*)&Kl[(lr)*136      + kk*32 + lg*8];
      bf16x8 k1f = *(const bf16x8*)&Kl[(16+lr)*136   + kk*32 + lg*8];
      s0 = __builtin_amdgcn_mfma_f32_16x16x32_bf16(qf[kk], k0f, s0, 0,0,0);
      s1 = __builtin_amdgcn_mfma_f32_16x16x32_bf16(qf[kk], k1f, s1, 0,0,0);
    }
    if(jt >= nfull){
#pragma unroll
      for(int r=0;r<4;r++){
        int rowa = TC + qw + lg*4 + r;   // absolute query position
        if(j0 + lr > rowa)      s0[r] = -1e30f;
        if(j0 + 16 + lr > rowa) s1[r] = -1e30f;
      }
    }
    float tmax[4];
#pragma unroll
    for(int r=0;r<4;r++) tmax[r] = fmaxf(s0[r], s1[r]);
#pragma unroll
    for(int d=1; d<16; d<<=1){
#pragma unroll
      for(int r=0;r<4;r++) tmax[r] = fmaxf(tmax[r], __shfl_xor(tmax[r], d, 64));
    }
    float alpha[4];
#pragma unroll
    for(int r=0;r<4;r++){
      float mn = fmaxf(mrun[r], tmax[r]);
      alpha[r] = __expf(mrun[r] - mn);
      mrun[r] = mn;
    }
#pragma unroll
    for(int r=0;r<4;r++){
      s0[r] = __expf(s0[r] - mrun[r]);
      s1[r] = __expf(s1[r] - mrun[r]);
    }
    float tsum[4];
#pragma unroll
    for(int r=0;r<4;r++) tsum[r] = s0[r] + s1[r];
#pragma unroll
    for(int d=1; d<16; d<<=1){
#pragma unroll
      for(int r=0;r<4;r++) tsum[r] += __shfl_xor(tsum[r], d, 64);
    }
#pragma unroll
    for(int r=0;r<4;r++) lrun[r] = lrun[r] * alpha[r] + tsum[r];
#pragma unroll
    for(int dt=0; dt<8; dt++)
#pragma unroll
      for(int r=0;r<4;r++) o[dt][r] *= alpha[r];
    // P -> LDS (accumulator layout) -> read back as MFMA A-fragment
#pragma unroll
    for(int r=0;r<4;r++){
      Pw[(lg*4 + r)*40 + lr]      = f2bf(s0[r]);
      Pw[(lg*4 + r)*40 + 16 + lr] = f2bf(s1[r]);
    }
    bf16x8 pf = *(const bf16x8*)&Pw[lr*40 + lg*8];
#pragma unroll
    for(int dt=0; dt<8; dt++){
      bf16x8 vf = *(const bf16x8*)&Vl[(dt*16 + lr)*40 + lg*8];
      o[dt] = __builtin_amdgcn_mfma_f32_16x16x32_bf16(pf, vf, o[dt], 0,0,0);
    }
    __syncthreads();
  }
  float inv[4];
#pragma unroll
  for(int r=0;r<4;r++) inv[r] = 1.f / lrun[r];
#pragma unroll
  for(int dt=0; dt<8; dt++){
#pragma unroll
    for(int r=0;r<4;r++){
      int t = qw + lg*4 + r;
      int d = dt*16 + lr;
      attn_out[((size_t)(b*Tt + t))*Cc + h*Dd + d] = f2bf(o[dt][r] * inv[r]);
    }
  }
}

extern "C" void kernel_launch(void* const* d_in, const int* in_sizes, int n_in,
                              void* d_out, int out_size, void* d_ws, size_t ws_size,
                              hipStream_t stream){
  const float* x       = (const float*)d_in[0];
  const float* cache_k = (const float*)d_in[1];
  const float* cache_v = (const float*)d_in[2];
  const float* W_qkv   = (const float*)d_in[3];
  const float* W_proj  = (const float*)d_in[4];
  const float* b_proj  = (const float*)d_in[5];

  float* out   = (float*)d_out;
  float* out_k = out   + (size_t)Bb*Tt*Cc;       // 4,194,304
  float* out_v = out_k + (size_t)Bb*Hh*CTX*Dd;   // +8,388,608

  // ws layout (bf16 elements), total 64 MiB
  unsigned short* WqkvT  = (unsigned short*)d_ws;               // [6144][2048]
  unsigned short* WprojT = WqkvT  + (size_t)6144*2048;          // [2048][2048]
  unsigned short* q_ws   = WprojT + (size_t)2048*2048;          // [B,H,T,D] (pre-scaled)
  unsigned short* Vt_ws  = q_ws   + (size_t)Bb*Hh*Tt*Dd;        // [B,H,D,CTX]
  unsigned short* attn_ws= Vt_ws  + (size_t)Bb*Hh*Dd*CTX;       // [B*T][C]
  if(ws_size < (size_t)67108864) return; // need 64 MiB scratch

  transpose_f32_bf16<<<dim3(192,64,1), 256, 0, stream>>>(W_qkv,  WqkvT,  2048, 6144);
  transpose_f32_bf16<<<dim3(64,64,1),  256, 0, stream>>>(W_proj, WprojT, 2048, 2048);
  cache_copy<<<dim3(4096), 256, 0, stream>>>((const float4*)cache_k, (const float4*)cache_v,
                                             (float4*)out_k, (float4*)out_v);
  gemm_k<0,0><<<dim3(16,48), 256, 0, stream>>>(x, WqkvT, q_ws, out_k, out_v, nullptr, nullptr);
  // transpose full V (cache+new) per (b,h): [2048 keys][128 d] -> [128][2048] bf16
  transpose_f32_bf16<<<dim3(4,64,32), 256, 0, stream>>>(out_v, Vt_ws, 2048, 128);
  attn_k<<<dim3(16,16,2), 256, 0, stream>>>(q_ws, out_k, Vt_ws, attn_ws);
  gemm_k<1,1><<<dim3(16,16), 256, 0, stream>>>(attn_ws, WprojT, nullptr, nullptr, nullptr, b_proj, out);
}

// Round 2
// 254.040 us; speedup vs baseline: 1.2250x; 1.2250x over previous
//
#include <hip/hip_runtime.h>
#include <hip/hip_bf16.h>

typedef __attribute__((ext_vector_type(8))) short bf16x8;
typedef __attribute__((ext_vector_type(4))) float f32x4;
typedef __attribute__((ext_vector_type(16))) float f32x16;

#define DI __device__ __forceinline__

static constexpr int Bb  = 2;
static constexpr int Tt  = 1024;
static constexpr int Cc  = 2048;
static constexpr int Hh  = 16;
static constexpr int Dd  = 128;
static constexpr int TC  = 1024;   // cached tokens (seq_start)
static constexpr int CTX = 2048;   // total context
static constexpr float QSCALE = 0.08838834764831845f; // 1/sqrt(128)

DI unsigned short f2bf(float f){
  unsigned u = __builtin_bit_cast(unsigned, f);
  u += 0x7FFFu + ((u >> 16) & 1u);
  return (unsigned short)(u >> 16);
}
DI unsigned pk2(float a, float b){
  return (unsigned)f2bf(a) | ((unsigned)f2bf(b) << 16);
}
DI bf16x8 mk4(unsigned a, unsigned b, unsigned c, unsigned d){
  union{ unsigned u[4]; bf16x8 v; } x;
  x.u[0]=a; x.u[1]=b; x.u[2]=c; x.u[3]=d; return x.v;
}
DI f32x16 mfma32(bf16x8 a, bf16x8 b, f32x16 c){
  return __builtin_amdgcn_mfma_f32_32x32x16_bf16(a, b, c, 0, 0, 0);
}
DI void gld16(const void* g, void* l){
  __builtin_amdgcn_global_load_lds(
      (const __attribute__((address_space(1))) unsigned int*)g,
      (__attribute__((address_space(3))) unsigned int*)l, 16, 0, 0);
}

// ---- transpose fp32 [R][C] -> bf16 [C][R] with swizzled k-units ----
// MODE 0 (GEMM B^T): within 32-elem k-groups, unit(8) position = u ^ ((outrow>>1)&3)
// MODE 1 (V^T for attn): within 64-elem key-groups, unit position = u ^ (outrow&7)
template<int MODE>
__global__ __launch_bounds__(256) void transpose_k(
    const float* __restrict__ in, unsigned short* __restrict__ out, int R, int C){
  __shared__ unsigned short tile[32][33];
  size_t boff = (size_t)blockIdx.z * R * C;
  in += boff; out += boff;
  int r0 = blockIdx.y * 32, c0 = blockIdx.x * 32;
  int tx = threadIdx.x & 31, ty = threadIdx.x >> 5;
#pragma unroll
  for(int i=0;i<4;i++){
    int r = r0 + ty + i*8;
    tile[ty + i*8][tx] = f2bf(in[(size_t)r * C + c0 + tx]);
  }
  __syncthreads();
#pragma unroll
  for(int i=0;i<4;i++){
    int c = c0 + ty + i*8;     // out row
    int k = r0 + tx;           // out col (logical)
    int kp;
    if constexpr (MODE == 0)
      kp = (k & ~24) | ((((k>>3)&3) ^ ((c>>1)&3)) << 3);
    else
      kp = (k & ~56) | ((((k>>3)&7) ^ (c&7)) << 3);
    out[(size_t)c * R + kp] = tile[tx][ty + i*8];
  }
}

// ---- x fp32 -> bf16 with GEMM-A swizzle ----
__global__ __launch_bounds__(256) void xconv_k(
    const float4* __restrict__ x4, unsigned short* __restrict__ xbf){
  int idx = blockIdx.x * 256 + threadIdx.x;   // 2048*2048/4 threads
  int m = idx >> 9;
  int c4 = (idx & 511) * 4;
  float4 v = x4[idx];
  int cp = (c4 & ~24) | ((((c4>>3)&3) ^ ((m>>1)&3)) << 3);
  uint2 p; p.x = pk2(v.x, v.y); p.y = pk2(v.z, v.w);
  *(uint2*)(xbf + (size_t)m * Cc + cp) = p;
}

// ---- copy KV cache into fp32 outputs + swizzled bf16 K ----
__global__ __launch_bounds__(256) void cache_copy(
    const float4* __restrict__ ck, const float4* __restrict__ cv,
    float4* __restrict__ ok, float4* __restrict__ ov,
    unsigned short* __restrict__ Kws){
  int idx = blockIdx.x * 256 + threadIdx.x;
  const int per = TC * Dd / 4;                 // 32768 per (b,h)
  int bh = idx / per, r = idx - bh * per;
  int dst = bh * (CTX * Dd / 4) + r;
  float4 kv = ck[idx];
  ok[dst] = kv;
  ov[dst] = cv[idx];
  int key = r >> 5, dq = (r & 31) * 4;
  int dp = (((dq>>3) ^ (key&7)) << 3) | (dq & 7);
  uint2 p; p.x = pk2(kv.x, kv.y); p.y = pk2(kv.z, kv.w);
  *(uint2*)(Kws + ((size_t)bh * CTX + key) * Dd + dp) = p;
}

// ---- GEMM: C[m][n] = sum_k A[m][k]*W[k][n]; A,BT bf16 swizzled [row][K] ----
template<int EPI>
__global__ __launch_bounds__(256) void gemm_k(
    const unsigned short* __restrict__ A, const unsigned short* __restrict__ BT,
    unsigned short* __restrict__ q_ws, float* __restrict__ out_k,
    float* __restrict__ out_v, unsigned short* __restrict__ Kws,
    const float* __restrict__ bias, float* __restrict__ outp){
  constexpr int K = 2048;
  __shared__ unsigned short Al[2][128*32];
  __shared__ unsigned short Bl[2][128*32];
  int tid = threadIdx.x, lane = tid & 63, w = tid >> 6;
  int lr = lane & 15, lg = lane >> 4;
  int m0 = blockIdx.x * 128, n0 = blockIdx.y * 128;
  int wr = (w >> 1) * 64, wc = (w & 1) * 64;
  int swz = (lg ^ ((lr >> 1) & 3)) << 3;

  f32x4 acc[4][4];
#pragma unroll
  for(int i=0;i<4;i++)
#pragma unroll
    for(int j=0;j<4;j++) acc[i][j] = (f32x4){0.f,0.f,0.f,0.f};

  auto stage = [&](int buf, int k0){
#pragma unroll
    for(int li=0; li<2; li++){
      int rb = w*32 + li*16;
      gld16(A  + (size_t)(m0 + rb + (lane>>2))*K + k0 + (lane&3)*8, &Al[buf][rb*32]);
      gld16(BT + (size_t)(n0 + rb + (lane>>2))*K + k0 + (lane&3)*8, &Bl[buf][rb*32]);
    }
  };
  stage(0, 0);
  __syncthreads();
  int buf = 0;
  for(int k0 = 0; k0 < K; k0 += 32){
    if(k0 + 32 < K) stage(buf^1, k0 + 32);
    bf16x8 af[4], bfr[4];
#pragma unroll
    for(int mi=0;mi<4;mi++) af[mi]  = *(const bf16x8*)&Al[buf][(wr+mi*16+lr)*32 + swz];
#pragma unroll
    for(int ni=0;ni<4;ni++) bfr[ni] = *(const bf16x8*)&Bl[buf][(wc+ni*16+lr)*32 + swz];
#pragma unroll
    for(int mi=0;mi<4;mi++)
#pragma unroll
      for(int ni=0;ni<4;ni++)
        acc[mi][ni] = __builtin_amdgcn_mfma_f32_16x16x32_bf16(af[mi], bfr[ni], acc[mi][ni], 0, 0, 0);
    __syncthreads();
    buf ^= 1;
  }

#pragma unroll
  for(int mi=0;mi<4;mi++){
#pragma unroll
    for(int ni=0;ni<4;ni++){
      int n = n0 + wc + ni*16 + lr;
#pragma unroll
      for(int r=0;r<4;r++){
        int mrow = m0 + wr + mi*16 + lg*4 + r;
        float v = acc[mi][ni][r];
        if constexpr (EPI == 0){
          int seg = n >> 11;
          int h = (n >> 7) & 15, d = n & 127;
          int b = mrow >> 10, t = mrow & 1023;
          if(seg == 0){
            q_ws[((size_t)(b*Hh + h)*Tt + t)*Dd + d] = f2bf(v * QSCALE);
          } else if(seg == 1){
            int key = TC + t;
            size_t base = (size_t)(b*Hh + h)*CTX + key;
            out_k[base*Dd + d] = v;
            int dp = (((d>>3) ^ (key&7)) << 3) | (d & 7);
            Kws[base*Dd + dp] = f2bf(v);
          } else {
            out_v[((size_t)(b*Hh + h)*CTX + TC + t)*Dd + d] = v;
          }
        } else {
          outp[(size_t)mrow * Cc + n] = v + bias[n];
        }
      }
    }
  }
}

// ---- flash attention, swapped-QK 32x32, 4 waves x 32q, key-split x2 ----
__global__ __launch_bounds__(256, 2) void attn_k(
    const unsigned short* __restrict__ q_ws,
    const unsigned short* __restrict__ Kws,
    const unsigned short* __restrict__ Vt,
    float* __restrict__ O0, float* __restrict__ O1,
    float* __restrict__ ml){
  __shared__ unsigned short Kl[2][64*128];   // [key][128] swizzled
  __shared__ unsigned short Vl[2][128*64];   // [d][64]  swizzled
  int tid = threadIdx.x, lane = tid & 63, w = tid >> 6;
  int l31 = lane & 31, hi = lane >> 5, r7 = l31 & 7;
  int qt = blockIdx.x, split = blockIdx.y, bh = blockIdx.z;
  int q0b = qt * 128, qw0 = q0b + w * 32;
  const unsigned short* Kb = Kws + (size_t)bh * CTX * Dd;
  const unsigned short* Vb = Vt  + (size_t)bh * Dd * CTX;

  // hoisted Q fragments (pre-scaled bf16)
  const unsigned short* qp = q_ws + ((size_t)bh * Tt + qw0 + l31) * Dd + hi * 8;
  bf16x8 qf[8];
#pragma unroll
  for(int ks=0;ks<8;ks++) qf[ks] = *(const bf16x8*)(qp + ks*16);

  f32x16 o[4];
#pragma unroll
  for(int dt=0;dt<4;dt++)
#pragma unroll
    for(int r=0;r<16;r++) o[dt][r] = 0.f;
  float m = -3e38f, l = 0.f;

  int nts = ((TC + q0b + 128) >> 6) >> 1;   // tiles for this split (equal split)

  auto stageK = [&](int buf, int j0){
#pragma unroll
    for(int li=0; li<4; li++){
      gld16(Kb + (size_t)(j0 + w*16 + li*4 + (lane>>4))*Dd + (lane&15)*8,
            &Kl[buf][(w*16 + li*4)*128]);
    }
  };
  auto stageV = [&](int buf, int j0){
#pragma unroll
    for(int li=0; li<4; li++){
      gld16(Vb + (size_t)(w*32 + li*8 + (lane>>3))*CTX + j0 + (lane&7)*8,
            &Vl[buf][(w*32 + li*8)*64]);
    }
  };

  stageK(0, split*64); stageV(0, split*64);
  __syncthreads();
  int buf = 0;
#pragma unroll 1
  for(int t = 0; t < nts; t++){
    int j0 = (2*t + split) * 64;
    if(t + 1 < nts){ stageK(buf^1, j0 + 128); stageV(buf^1, j0 + 128); }

    if(j0 <= TC + qw0 + 31){    // not fully masked for this wave
      f32x16 s0, s1;
#pragma unroll
      for(int r=0;r<16;r++){ s0[r] = 0.f; s1[r] = 0.f; }
#pragma unroll
      for(int ks=0; ks<8; ks++){
        int ub = ((ks*2 + hi) ^ r7) << 3;
        bf16x8 kf0 = *(const bf16x8*)&Kl[buf][l31*128 + ub];
        bf16x8 kf1 = *(const bf16x8*)&Kl[buf][(32+l31)*128 + ub];
        s0 = mfma32(kf0, qf[ks], s0);
        s1 = mfma32(kf1, qf[ks], s1);
      }
      int qabs = TC + qw0 + l31;
      if(j0 + 63 > TC + qw0){
#pragma unroll
        for(int r=0;r<16;r++){
          int kk = (r&3) + 8*(r>>2) + 4*hi;
          if(j0 + kk > qabs)      s0[r] = -1e30f;
          if(j0 + 32 + kk > qabs) s1[r] = -1e30f;
        }
      }
      // row max (row = q = l31; partner lane holds other half of keys)
      float tm = fmaxf(s0[0], s1[0]);
#pragma unroll
      for(int r=1;r<16;r++) tm = fmaxf(tm, fmaxf(s0[r], s1[r]));
      tm = fmaxf(tm, __shfl_xor(tm, 32, 64));
      if(!__all(tm - m <= 8.f)){
        float mn = fmaxf(m, tm);
        float alpha = __expf(m - mn);
        m = mn;
        l *= alpha;
        float ar[16];
#pragma unroll
        for(int r=0;r<16;r++){
          int kk = (r&3) + 8*(r>>2) + 4*hi;
          ar[r] = __shfl(alpha, kk, 64);
        }
#pragma unroll
        for(int dt=0;dt<4;dt++)
#pragma unroll
          for(int r=0;r<16;r++) o[dt][r] *= ar[r];
      }
#pragma unroll
      for(int r=0;r<16;r++){ s0[r] = __expf(s0[r] - m); s1[r] = __expf(s1[r] - m); }
      float ts = 0.f;
#pragma unroll
      for(int r=0;r<16;r++) ts += s0[r] + s1[r];
      ts += __shfl_xor(ts, 32, 64);
      l += ts;
      // pack P and PV
#pragma unroll
      for(int ks16=0; ks16<4; ks16++){
        f32x16 p = (ks16 & 2) ? s1 : s0;
        int fb = (ks16 & 1) * 8;
        unsigned e0 = pk2(p[fb+0], p[fb+1]);
        unsigned e1 = pk2(p[fb+2], p[fb+3]);
        unsigned e2 = pk2(p[fb+4], p[fb+5]);
        unsigned e3 = pk2(p[fb+6], p[fb+7]);
        unsigned x0 = __shfl_xor(e0, 32, 64);
        unsigned x1 = __shfl_xor(e1, 32, 64);
        unsigned x2 = __shfl_xor(e2, 32, 64);
        unsigned x3 = __shfl_xor(e3, 32, 64);
        bf16x8 pa = mk4(hi ? x2 : e0, hi ? x3 : e1, hi ? e2 : x0, hi ? e3 : x1);
        int ub = ((ks16*2 + hi) ^ r7) << 3;
#pragma unroll
        for(int dt=0; dt<4; dt++){
          bf16x8 vf = *(const bf16x8*)&Vl[buf][(dt*32 + l31)*64 + ub];
          o[dt] = mfma32(pa, vf, o[dt]);
        }
      }
    }
    __syncthreads();
    buf ^= 1;
  }

  float* Op = split ? O1 : O0;
#pragma unroll
  for(int dt=0; dt<4; dt++){
#pragma unroll
    for(int r=0; r<16; r++){
      int q = qw0 + (r&3) + 8*(r>>2) + 4*hi;
      Op[((size_t)bh*Tt + q)*Dd + dt*32 + l31] = o[dt][r];
    }
  }
  if(lane < 32){
    float* mlp = ml + (((size_t)split*32 + bh)*Tt + qw0 + l31)*2;
    mlp[0] = m; mlp[1] = l;
  }
}

// ---- combine split partials -> bf16 attn_ws (swizzled for proj GEMM) ----
__global__ __launch_bounds__(256) void combine_k(
    const float* __restrict__ O0, const float* __restrict__ O1,
    const float* __restrict__ ml, unsigned short* __restrict__ attn_ws){
  int tid = threadIdx.x;
  int d = tid & 127, rl = tid >> 7;
  int row = blockIdx.x * 2 + rl;          // bh*1024 + t
  int bh = row >> 10, t = row & 1023;
  const float* p0 = ml + ((size_t)bh * Tt + t) * 2;
  const float* p1 = ml + (((size_t)32 + bh) * Tt + t) * 2;
  float m0 = p0[0], l0 = p0[1], m1 = p1[0], l1 = p1[1];
  float M = fmaxf(m0, m1);
  float e0 = __expf(m0 - M), e1 = __expf(m1 - M);
  float inv = 1.f / (l0*e0 + l1*e1);
  size_t off = (size_t)row * Dd + d;
  float v = (O0[off]*e0 + O1[off]*e1) * inv;
  int b = bh >> 4, h = bh & 15;
  int mrow = b * Tt + t;
  int c = h * Dd + d;
  int cp = (c & ~24) | ((((c>>3)&3) ^ ((mrow>>1)&3)) << 3);
  attn_ws[(size_t)mrow * Cc + cp] = f2bf(v);
}

extern "C" void kernel_launch(void* const* d_in, const int* in_sizes, int n_in,
                              void* d_out, int out_size, void* d_ws, size_t ws_size,
                              hipStream_t stream){
  const float* x       = (const float*)d_in[0];
  const float* cache_k = (const float*)d_in[1];
  const float* cache_v = (const float*)d_in[2];
  const float* W_qkv   = (const float*)d_in[3];
  const float* W_proj  = (const float*)d_in[4];
  const float* b_proj  = (const float*)d_in[5];

  float* out   = (float*)d_out;
  float* out_k = out   + (size_t)Bb*Tt*Cc;
  float* out_v = out_k + (size_t)Bb*Hh*CTX*Dd;

  if(ws_size < (size_t)67108864) return;  // need 64 MiB scratch
  char* ws = (char*)d_ws;
  // [0, 25165824): WqkvT; dead after QKV gemm -> O1 (16.8M) + ml (at +16777216)
  unsigned short* WqkvT  = (unsigned short*)(ws);
  unsigned short* WprojT = (unsigned short*)(ws + 25165824);  // q_ws region, written late
  unsigned short* q_ws   = (unsigned short*)(ws + 25165824);
  unsigned short* Kws    = (unsigned short*)(ws + 33554432);
  unsigned short* x_bf   = (unsigned short*)(ws + 50331648);  // E region
  unsigned short* Vt_ws  = (unsigned short*)(ws + 50331648);  // overwrites x_bf
  unsigned short* attn_ws= (unsigned short*)(ws + 50331648);  // overwrites Vt after attn
  float* O0 = out;                                            // out slot as scratch
  float* O1 = (float*)(ws);
  float* ml = (float*)(ws + 16777216);

  transpose_k<0><<<dim3(192,64,1), 256, 0, stream>>>(W_qkv, WqkvT, 2048, 6144);
  xconv_k<<<dim3(4096), 256, 0, stream>>>((const float4*)x, x_bf);
  cache_copy<<<dim3(4096), 256, 0, stream>>>((const float4*)cache_k, (const float4*)cache_v,
                                             (float4*)out_k, (float4*)out_v, Kws);
  gemm_k<0><<<dim3(16,48), 256, 0, stream>>>(x_bf, WqkvT, q_ws, out_k, out_v, Kws,
                                             nullptr, nullptr);
  transpose_k<1><<<dim3(4,64,32), 256, 0, stream>>>(out_v, Vt_ws, 2048, 128);
  attn_k<<<dim3(8,2,32), 256, 0, stream>>>(q_ws, Kws, Vt_ws, O0, O1, ml);
  transpose_k<0><<<dim3(64,64,1), 256, 0, stream>>>(W_proj, WprojT, 2048, 2048);
  combine_k<<<dim3(16384), 256, 0, stream>>>(O0, O1, ml, attn_ws);
  gemm_k<1><<<dim3(16,16), 256, 0, stream>>>(attn_ws, WprojT, nullptr, nullptr, nullptr,
                                             nullptr, b_proj, out);
}

// Round 3
// 222.130 us; speedup vs baseline: 1.4010x; 1.1437x over previous
//
#include <hip/hip_runtime.h>
#include <hip/hip_bf16.h>

typedef __attribute__((ext_vector_type(8))) short bf16x8;
typedef __attribute__((ext_vector_type(4))) float f32x4;
typedef __attribute__((ext_vector_type(16))) float f32x16;

#define DI __device__ __forceinline__

static constexpr int Bb  = 2;
static constexpr int Tt  = 1024;
static constexpr int Cc  = 2048;
static constexpr int Hh  = 16;
static constexpr int Dd  = 128;
static constexpr int TC  = 1024;   // cached tokens (seq_start)
static constexpr int CTX = 2048;   // total context
static constexpr float QSCALE = 0.08838834764831845f; // 1/sqrt(128)

DI unsigned short f2bf(float f){
  unsigned u = __builtin_bit_cast(unsigned, f);
  u += 0x7FFFu + ((u >> 16) & 1u);
  return (unsigned short)(u >> 16);
}
DI unsigned pk2(float a, float b){
  return (unsigned)f2bf(a) | ((unsigned)f2bf(b) << 16);
}
DI bf16x8 mk4(unsigned a, unsigned b, unsigned c, unsigned d){
  union{ unsigned u[4]; bf16x8 v; } x;
  x.u[0]=a; x.u[1]=b; x.u[2]=c; x.u[3]=d; return x.v;
}
DI f32x16 mfma32(bf16x8 a, bf16x8 b, f32x16 c){
  return __builtin_amdgcn_mfma_f32_32x32x16_bf16(a, b, c, 0, 0, 0);
}
#define MFMA16(a,b,c) __builtin_amdgcn_mfma_f32_16x16x32_bf16(a,b,c,0,0,0)
DI void gld16(const void* g, void* l){
  __builtin_amdgcn_global_load_lds(
      (const __attribute__((address_space(1))) unsigned int*)g,
      (__attribute__((address_space(3))) unsigned int*)l, 16, 0, 0);
}

// ---- transpose fp32 [R][C] -> bf16 [C][R] with swizzled k-units ----
// MODE 0 (proj B^T, BK=32 kernel): unit(8) pos = u ^ ((outrow>>1)&3) in 32-elem groups
// MODE 1 (8-phase GEMM / attn V^T): unit pos = u ^ (outrow&7) in 64-elem groups
template<int MODE>
__global__ __launch_bounds__(256) void transpose_k(
    const float* __restrict__ in, unsigned short* __restrict__ out, int R, int C){
  __shared__ unsigned short tile[32][33];
  size_t boff = (size_t)blockIdx.z * R * C;
  in += boff; out += boff;
  int r0 = blockIdx.y * 32, c0 = blockIdx.x * 32;
  int tx = threadIdx.x & 31, ty = threadIdx.x >> 5;
#pragma unroll
  for(int i=0;i<4;i++){
    int r = r0 + ty + i*8;
    tile[ty + i*8][tx] = f2bf(in[(size_t)r * C + c0 + tx]);
  }
  __syncthreads();
#pragma unroll
  for(int i=0;i<4;i++){
    int c = c0 + ty + i*8;     // out row
    int k = r0 + tx;           // out col (logical)
    int kp;
    if constexpr (MODE == 0)
      kp = (k & ~24) | ((((k>>3)&3) ^ ((c>>1)&3)) << 3);
    else
      kp = (k & ~56) | ((((k>>3)&7) ^ (c&7)) << 3);
    out[(size_t)c * R + kp] = tile[tx][ty + i*8];
  }
}

// ---- x fp32 -> bf16 with 8-phase GEMM A swizzle (8-unit, row&7) ----
__global__ __launch_bounds__(256) void xconv_k(
    const float4* __restrict__ x4, unsigned short* __restrict__ xbf){
  int idx = blockIdx.x * 256 + threadIdx.x;   // 2048*2048/4 threads
  int m = idx >> 9;
  int c4 = (idx & 511) * 4;
  float4 v = x4[idx];
  int cp = ((((c4>>3) ^ (m&7)) << 3)) | (c4 & 7);
  uint2 p; p.x = pk2(v.x, v.y); p.y = pk2(v.z, v.w);
  *(uint2*)(xbf + (size_t)m * Cc + cp) = p;
}

// ---- copy KV cache into fp32 outputs + swizzled bf16 K ----
__global__ __launch_bounds__(256) void cache_copy(
    const float4* __restrict__ ck, const float4* __restrict__ cv,
    float4* __restrict__ ok, float4* __restrict__ ov,
    unsigned short* __restrict__ Kws){
  int idx = blockIdx.x * 256 + threadIdx.x;
  const int per = TC * Dd / 4;                 // 32768 per (b,h)
  int bh = idx / per, r = idx - bh * per;
  int dst = bh * (CTX * Dd / 4) + r;
  float4 kv = ck[idx];
  ok[dst] = kv;
  ov[dst] = cv[idx];
  int key = r >> 5, dq = (r & 31) * 4;
  int dp = (((dq>>3) ^ (key&7)) << 3) | (dq & 7);
  uint2 p; p.x = pk2(kv.x, kv.y); p.y = pk2(kv.z, kv.w);
  *(uint2*)(Kws + ((size_t)bh * CTX + key) * Dd + dp) = p;
}

// ================= 256x256 8-phase GEMM (QKV) =================
// C[m][n] = sum_k A[m][k]*W[k][n]; A, BT bf16 with u^=(row&7) unit swizzle.
// M=2048 N=6144 K=2048. Grid 192 (8 m x 24 n), 512 threads, 128KiB LDS.
__global__ __launch_bounds__(512) void gemm8_k(
    const unsigned short* __restrict__ A, const unsigned short* __restrict__ BT,
    unsigned short* __restrict__ q_ws, float* __restrict__ out_k,
    float* __restrict__ out_v, unsigned short* __restrict__ Kws){
  constexpr int K = 2048;
  __shared__ unsigned short lds[65536];        // A: [0,32768) B: [32768,65536)
  int tid = threadIdx.x, lane = tid & 63, w = tid >> 6;
  int lr = lane & 15, lg = lane >> 4;
  int wm = w >> 2, wn = w & 3;
  int bid = blockIdx.x;                        // 192 blocks, 192%8==0
  int swz = (bid & 7) * 24 + (bid >> 3);       // bijective XCD swizzle
  int m0 = (swz & 7) * 256;
  int n0 = (swz >> 3) * 256;

  int r8 = lane >> 3, c8 = (lane & 7) * 8;
  const unsigned short* Asrc = A  + (size_t)(m0 + w*16 + r8)*K + c8;
  const unsigned short* Bsrc = BT + (size_t)(n0 + w*16 + r8)*K + c8;
  unsigned short* ldsA = lds;
  unsigned short* ldsB = lds + 32768;

  auto stgA = [&](int b, int h, int kt){
    const unsigned short* s = Asrc + (size_t)(h*128)*K + kt*64;
    unsigned short* d = ldsA + b*16384 + h*8192 + w*1024;
    gld16(s, d);
    gld16(s + (size_t)8*K, d + 512);
  };
  auto stgB = [&](int b, int h, int kt){
    const unsigned short* s = Bsrc + (size_t)(h*128)*K + kt*64;
    unsigned short* d = ldsB + b*16384 + h*8192 + w*1024;
    gld16(s, d);
    gld16(s + (size_t)8*K, d + 512);
  };

  int ua0 = ( lg      ^ (lr & 7)) * 8;   // kk=0 physical unit offset (elems)
  int ua1 = ((4 + lg) ^ (lr & 7)) * 8;   // kk=1
  const unsigned short* apA = ldsA + (wm*128 + lr)*64;
  const unsigned short* apB = ldsB + (wn*64  + lr)*64;

  f32x4 acc[8][4];
#pragma unroll
  for(int i=0;i<8;i++)
#pragma unroll
    for(int j=0;j<4;j++) acc[i][j] = (f32x4){0.f,0.f,0.f,0.f};
  bf16x8 bfr[4][2];

  // prologue: K-tile0 fully + B(1); leave B(1) in flight
  stgA(0,0,0); stgA(0,1,0); stgB(0,0,0); stgB(0,1,0); stgB(1,0,1); stgB(1,1,1);
  asm volatile("s_waitcnt vmcnt(4)" ::: "memory");
  __builtin_amdgcn_s_barrier();

#define PHASE(BUF, Q, STAGE, VM)                                           \
  {                                                                        \
    const unsigned short* pa = apA + (BUF)*16384 + (Q)*2048;               \
    bf16x8 a00 = *(const bf16x8*)(pa + ua0);                               \
    bf16x8 a10 = *(const bf16x8*)(pa + 1024 + ua0);                        \
    bf16x8 a01 = *(const bf16x8*)(pa + ua1);                               \
    bf16x8 a11 = *(const bf16x8*)(pa + 1024 + ua1);                        \
    if((Q) == 0){                                                          \
      const unsigned short* pb = apB + (BUF)*16384;                        \
      _Pragma("unroll")                                                    \
      for(int ni=0;ni<4;ni++){                                             \
        bfr[ni][0] = *(const bf16x8*)(pb + ni*1024 + ua0);                 \
        bfr[ni][1] = *(const bf16x8*)(pb + ni*1024 + ua1);                 \
      }                                                                    \
    }                                                                      \
    STAGE;                                                                 \
    __builtin_amdgcn_s_barrier();                                          \
    asm volatile("s_waitcnt lgkmcnt(0)" ::: "memory");                     \
    __builtin_amdgcn_s_setprio(1);                                         \
    _Pragma("unroll")                                                      \
    for(int ni=0;ni<4;ni++){                                               \
      acc[2*(Q)][ni]   = MFMA16(a00, bfr[ni][0], acc[2*(Q)][ni]);          \
      acc[2*(Q)+1][ni] = MFMA16(a10, bfr[ni][0], acc[2*(Q)+1][ni]);        \
    }                                                                      \
    _Pragma("unroll")                                                      \
    for(int ni=0;ni<4;ni++){                                               \
      acc[2*(Q)][ni]   = MFMA16(a01, bfr[ni][1], acc[2*(Q)][ni]);          \
      acc[2*(Q)+1][ni] = MFMA16(a11, bfr[ni][1], acc[2*(Q)+1][ni]);        \
    }                                                                      \
    __builtin_amdgcn_s_setprio(0);                                         \
    VM;                                                                    \
    __builtin_amdgcn_s_barrier();                                          \
  }

#define VMW asm volatile("s_waitcnt vmcnt(4)" ::: "memory")

#pragma unroll 1
  for(int i=0;i<16;i++){
    int t1 = 2*i+1, t2 = (2*i+2)&31, t3 = (2*i+3)&31;
    PHASE(0, 0, stgA(1,0,t1), );
    PHASE(0, 1, stgA(1,1,t1), );
    PHASE(0, 2, stgB(0,0,t2), );
    PHASE(0, 3, stgB(0,1,t2), VMW);
    PHASE(1, 0, stgA(0,0,t2), );
    PHASE(1, 1, stgA(0,1,t2), );
    PHASE(1, 2, stgB(1,0,t3), );
    PHASE(1, 3, stgB(1,1,t3), VMW);
  }
#undef PHASE
#undef VMW
  asm volatile("s_waitcnt vmcnt(0)" ::: "memory");

  // epilogue: QKV scatter
#pragma unroll
  for(int mi=0;mi<8;mi++){
#pragma unroll
    for(int ni=0;ni<4;ni++){
      int n = n0 + wn*64 + ni*16 + lr;
      int seg = n >> 11;
      int h = (n >> 7) & 15, d = n & 127;
#pragma unroll
      for(int r=0;r<4;r++){
        int mrow = m0 + wm*128 + mi*16 + lg*4 + r;
        float v = acc[mi][ni][r];
        int b = mrow >> 10, t = mrow & 1023;
        if(seg == 0){
          q_ws[((size_t)(b*Hh + h)*Tt + t)*Dd + d] = f2bf(v * QSCALE);
        } else if(seg == 1){
          int key = TC + t;
          size_t base = (size_t)(b*Hh + h)*CTX + key;
          out_k[base*Dd + d] = v;
          int dp = (((d>>3) ^ (key&7)) << 3) | (d & 7);
          Kws[base*Dd + dp] = f2bf(v);
        } else {
          out_v[((size_t)(b*Hh + h)*CTX + TC + t)*Dd + d] = v;
        }
      }
    }
  }
}

// ---- 128x128 BK=32 GEMM (proj): A, BT bf16 MODE-0 swizzled [row][K] ----
__global__ __launch_bounds__(256) void gemmp_k(
    const unsigned short* __restrict__ A, const unsigned short* __restrict__ BT,
    const float* __restrict__ bias, float* __restrict__ outp){
  constexpr int K = 2048;
  __shared__ unsigned short Al[2][128*32];
  __shared__ unsigned short Bl[2][128*32];
  int tid = threadIdx.x, lane = tid & 63, w = tid >> 6;
  int lr = lane & 15, lg = lane >> 4;
  int m0 = blockIdx.x * 128, n0 = blockIdx.y * 128;
  int wr = (w >> 1) * 64, wc = (w & 1) * 64;
  int swz = (lg ^ ((lr >> 1) & 3)) << 3;

  f32x4 acc[4][4];
#pragma unroll
  for(int i=0;i<4;i++)
#pragma unroll
    for(int j=0;j<4;j++) acc[i][j] = (f32x4){0.f,0.f,0.f,0.f};

  auto stage = [&](int buf, int k0){
#pragma unroll
    for(int li=0; li<2; li++){
      int rb = w*32 + li*16;
      gld16(A  + (size_t)(m0 + rb + (lane>>2))*K + k0 + (lane&3)*8, &Al[buf][rb*32]);
      gld16(BT + (size_t)(n0 + rb + (lane>>2))*K + k0 + (lane&3)*8, &Bl[buf][rb*32]);
    }
  };
  stage(0, 0);
  __syncthreads();
  int buf = 0;
  for(int k0 = 0; k0 < K; k0 += 32){
    if(k0 + 32 < K) stage(buf^1, k0 + 32);
    bf16x8 af[4], bfr[4];
#pragma unroll
    for(int mi=0;mi<4;mi++) af[mi]  = *(const bf16x8*)&Al[buf][(wr+mi*16+lr)*32 + swz];
#pragma unroll
    for(int ni=0;ni<4;ni++) bfr[ni] = *(const bf16x8*)&Bl[buf][(wc+ni*16+lr)*32 + swz];
#pragma unroll
    for(int mi=0;mi<4;mi++)
#pragma unroll
      for(int ni=0;ni<4;ni++)
        acc[mi][ni] = MFMA16(af[mi], bfr[ni], acc[mi][ni]);
    __syncthreads();
    buf ^= 1;
  }

#pragma unroll
  for(int mi=0;mi<4;mi++){
#pragma unroll
    for(int ni=0;ni<4;ni++){
      int n = n0 + wc + ni*16 + lr;
#pragma unroll
      for(int r=0;r<4;r++){
        int mrow = m0 + wr + mi*16 + lg*4 + r;
        outp[(size_t)mrow * Cc + n] = acc[mi][ni][r] + bias[n];
      }
    }
  }
}

// ---- flash attention, swapped-QK 32x32, 4 waves x 32q, key-split x2 ----
__global__ __launch_bounds__(256, 2) void attn_k(
    const unsigned short* __restrict__ q_ws,
    const unsigned short* __restrict__ Kws,
    const unsigned short* __restrict__ Vt,
    float* __restrict__ O0, float* __restrict__ O1,
    float* __restrict__ ml){
  __shared__ unsigned short Kl[2][64*128];   // [key][128] swizzled
  __shared__ unsigned short Vl[2][128*64];   // [d][64]  swizzled
  int tid = threadIdx.x, lane = tid & 63, w = tid >> 6;
  int l31 = lane & 31, hi = lane >> 5, r7 = l31 & 7;
  int qt = blockIdx.x, split = blockIdx.y, bh = blockIdx.z;
  int q0b = qt * 128, qw0 = q0b + w * 32;
  const unsigned short* Kb = Kws + (size_t)bh * CTX * Dd;
  const unsigned short* Vb = Vt  + (size_t)bh * Dd * CTX;

  const unsigned short* qp = q_ws + ((size_t)bh * Tt + qw0 + l31) * Dd + hi * 8;
  bf16x8 qf[8];
#pragma unroll
  for(int ks=0;ks<8;ks++) qf[ks] = *(const bf16x8*)(qp + ks*16);

  f32x16 o[4];
#pragma unroll
  for(int dt=0;dt<4;dt++)
#pragma unroll
    for(int r=0;r<16;r++) o[dt][r] = 0.f;
  float m = -3e38f, l = 0.f;

  int nts = ((TC + q0b + 128) >> 6) >> 1;   // tiles for this split

  auto stageK = [&](int buf, int j0){
#pragma unroll
    for(int li=0; li<4; li++){
      gld16(Kb + (size_t)(j0 + w*16 + li*4 + (lane>>4))*Dd + (lane&15)*8,
            &Kl[buf][(w*16 + li*4)*128]);
    }
  };
  auto stageV = [&](int buf, int j0){
#pragma unroll
    for(int li=0; li<4; li++){
      gld16(Vb + (size_t)(w*32 + li*8 + (lane>>3))*CTX + j0 + (lane&7)*8,
            &Vl[buf][(w*32 + li*8)*64]);
    }
  };

  stageK(0, split*64); stageV(0, split*64);
  __syncthreads();
  int buf = 0;
#pragma unroll 1
  for(int t = 0; t < nts; t++){
    int j0 = (2*t + split) * 64;
    if(t + 1 < nts){ stageK(buf^1, j0 + 128); stageV(buf^1, j0 + 128); }

    if(j0 <= TC + qw0 + 31){
      f32x16 s0, s1;
#pragma unroll
      for(int r=0;r<16;r++){ s0[r] = 0.f; s1[r] = 0.f; }
#pragma unroll
      for(int ks=0; ks<8; ks++){
        int ub = ((ks*2 + hi) ^ r7) << 3;
        bf16x8 kf0 = *(const bf16x8*)&Kl[buf][l31*128 + ub];
        bf16x8 kf1 = *(const bf16x8*)&Kl[buf][(32+l31)*128 + ub];
        s0 = mfma32(kf0, qf[ks], s0);
        s1 = mfma32(kf1, qf[ks], s1);
      }
      int qabs = TC + qw0 + l31;
      if(j0 + 63 > TC + qw0){
#pragma unroll
        for(int r=0;r<16;r++){
          int kk = (r&3) + 8*(r>>2) + 4*hi;
          if(j0 + kk > qabs)      s0[r] = -1e30f;
          if(j0 + 32 + kk > qabs) s1[r] = -1e30f;
        }
      }
      float tm = fmaxf(s0[0], s1[0]);
#pragma unroll
      for(int r=1;r<16;r++) tm = fmaxf(tm, fmaxf(s0[r], s1[r]));
      tm = fmaxf(tm, __shfl_xor(tm, 32, 64));
      if(!__all(tm - m <= 8.f)){
        float mn = fmaxf(m, tm);
        float alpha = __expf(m - mn);
        m = mn;
        l *= alpha;
        float ar[16];
#pragma unroll
        for(int r=0;r<16;r++){
          int kk = (r&3) + 8*(r>>2) + 4*hi;
          ar[r] = __shfl(alpha, kk, 64);
        }
#pragma unroll
        for(int dt=0;dt<4;dt++)
#pragma unroll
          for(int r=0;r<16;r++) o[dt][r] *= ar[r];
      }
#pragma unroll
      for(int r=0;r<16;r++){ s0[r] = __expf(s0[r] - m); s1[r] = __expf(s1[r] - m); }
      float ts = 0.f;
#pragma unroll
      for(int r=0;r<16;r++) ts += s0[r] + s1[r];
      ts += __shfl_xor(ts, 32, 64);
      l += ts;
#pragma unroll
      for(int ks16=0; ks16<4; ks16++){
        f32x16 p = (ks16 & 2) ? s1 : s0;
        int fb = (ks16 & 1) * 8;
        unsigned e0 = pk2(p[fb+0], p[fb+1]);
        unsigned e1 = pk2(p[fb+2], p[fb+3]);
        unsigned e2 = pk2(p[fb+4], p[fb+5]);
        unsigned e3 = pk2(p[fb+6], p[fb+7]);
        unsigned x0 = __shfl_xor(e0, 32, 64);
        unsigned x1 = __shfl_xor(e1, 32, 64);
        unsigned x2 = __shfl_xor(e2, 32, 64);
        unsigned x3 = __shfl_xor(e3, 32, 64);
        bf16x8 pa = mk4(hi ? x2 : e0, hi ? x3 : e1, hi ? e2 : x0, hi ? e3 : x1);
        int ub = ((ks16*2 + hi) ^ r7) << 3;
#pragma unroll
        for(int dt=0; dt<4; dt++){
          bf16x8 vf = *(const bf16x8*)&Vl[buf][(dt*32 + l31)*64 + ub];
          o[dt] = mfma32(pa, vf, o[dt]);
        }
      }
    }
    __syncthreads();
    buf ^= 1;
  }

  float* Op = split ? O1 : O0;
#pragma unroll
  for(int dt=0; dt<4; dt++){
#pragma unroll
    for(int r=0; r<16; r++){
      int q = qw0 + (r&3) + 8*(r>>2) + 4*hi;
      Op[((size_t)bh*Tt + q)*Dd + dt*32 + l31] = o[dt][r];
    }
  }
  if(lane < 32){
    float* mlp = ml + (((size_t)split*32 + bh)*Tt + qw0 + l31)*2;
    mlp[0] = m; mlp[1] = l;
  }
}

// ---- combine split partials -> bf16 attn_ws (MODE-0 swizzle for proj) ----
__global__ __launch_bounds__(256) void combine_k(
    const float* __restrict__ O0, const float* __restrict__ O1,
    const float* __restrict__ ml, unsigned short* __restrict__ attn_ws){
  int tid = threadIdx.x;
  int d = tid & 127, rl = tid >> 7;
  int row = blockIdx.x * 2 + rl;          // bh*1024 + t
  int bh = row >> 10, t = row & 1023;
  const float* p0 = ml + ((size_t)bh * Tt + t) * 2;
  const float* p1 = ml + (((size_t)32 + bh) * Tt + t) * 2;
  float m0 = p0[0], l0 = p0[1], m1 = p1[0], l1 = p1[1];
  float M = fmaxf(m0, m1);
  float e0 = __expf(m0 - M), e1 = __expf(m1 - M);
  float inv = 1.f / (l0*e0 + l1*e1);
  size_t off = (size_t)row * Dd + d;
  float v = (O0[off]*e0 + O1[off]*e1) * inv;
  int b = bh >> 4, h = bh & 15;
  int mrow = b * Tt + t;
  int c = h * Dd + d;
  int cp = (c & ~24) | ((((c>>3)&3) ^ ((mrow>>1)&3)) << 3);
  attn_ws[(size_t)mrow * Cc + cp] = f2bf(v);
}

extern "C" void kernel_launch(void* const* d_in, const int* in_sizes, int n_in,
                              void* d_out, int out_size, void* d_ws, size_t ws_size,
                              hipStream_t stream){
  const float* x       = (const float*)d_in[0];
  const float* cache_k = (const float*)d_in[1];
  const float* cache_v = (const float*)d_in[2];
  const float* W_qkv   = (const float*)d_in[3];
  const float* W_proj  = (const float*)d_in[4];
  const float* b_proj  = (const float*)d_in[5];

  float* out   = (float*)d_out;
  float* out_k = out   + (size_t)Bb*Tt*Cc;
  float* out_v = out_k + (size_t)Bb*Hh*CTX*Dd;

  if(ws_size < (size_t)67108864) return;  // need 64 MiB scratch
  char* ws = (char*)d_ws;
  unsigned short* WqkvT  = (unsigned short*)(ws);
  unsigned short* WprojT = (unsigned short*)(ws + 25165824);  // q_ws region, written late
  unsigned short* q_ws   = (unsigned short*)(ws + 25165824);
  unsigned short* Kws    = (unsigned short*)(ws + 33554432);
  unsigned short* x_bf   = (unsigned short*)(ws + 50331648);
  unsigned short* Vt_ws  = (unsigned short*)(ws + 50331648);  // overwrites x_bf
  unsigned short* attn_ws= (unsigned short*)(ws + 50331648);  // overwrites Vt after attn
  float* O0 = out;                                            // out slot as scratch
  float* O1 = (float*)(ws);
  float* ml = (float*)(ws + 16777216);

  transpose_k<1><<<dim3(192,64,1), 256, 0, stream>>>(W_qkv, WqkvT, 2048, 6144);
  xconv_k<<<dim3(4096), 256, 0, stream>>>((const float4*)x, x_bf);
  cache_copy<<<dim3(4096), 256, 0, stream>>>((const float4*)cache_k, (const float4*)cache_v,
                                             (float4*)out_k, (float4*)out_v, Kws);
  gemm8_k<<<dim3(192), 512, 0, stream>>>(x_bf, WqkvT, q_ws, out_k, out_v, Kws);
  transpose_k<1><<<dim3(4,64,32), 256, 0, stream>>>(out_v, Vt_ws, 2048, 128);
  attn_k<<<dim3(8,2,32), 256, 0, stream>>>(q_ws, Kws, Vt_ws, O0, O1, ml);
  transpose_k<0><<<dim3(64,64,1), 256, 0, stream>>>(W_proj, WprojT, 2048, 2048);
  combine_k<<<dim3(16384), 256, 0, stream>>>(O0, O1, ml, attn_ws);
  gemmp_k<<<dim3(16,16), 256, 0, stream>>>(attn_ws, WprojT, b_proj, out);
}

// Round 4
// 219.560 us; speedup vs baseline: 1.4174x; 1.0117x over previous
//
#include <hip/hip_runtime.h>
#include <hip/hip_bf16.h>

typedef __attribute__((ext_vector_type(8))) short bf16x8;
typedef __attribute__((ext_vector_type(4))) float f32x4;
typedef __attribute__((ext_vector_type(16))) float f32x16;

#define DI __device__ __forceinline__

static constexpr int Bb  = 2;
static constexpr int Tt  = 1024;
static constexpr int Cc  = 2048;
static constexpr int Hh  = 16;
static constexpr int Dd  = 128;
static constexpr int TC  = 1024;   // cached tokens (seq_start)
static constexpr int CTX = 2048;   // total context
static constexpr int LDP = 2112;   // padded row stride for GEMM operands (4224B, kills 4KB camping)
static constexpr int VS  = 2080;   // padded Vt row stride (4160B)
static constexpr float QSCALE = 0.08838834764831845f; // 1/sqrt(128)

DI unsigned short f2bf(float f){
  unsigned u = __builtin_bit_cast(unsigned, f);
  u += 0x7FFFu + ((u >> 16) & 1u);
  return (unsigned short)(u >> 16);
}
DI float bf2f(unsigned short s){
  return __builtin_bit_cast(float, (unsigned)s << 16);
}
DI unsigned pk2(float a, float b){
  return (unsigned)f2bf(a) | ((unsigned)f2bf(b) << 16);
}
DI bf16x8 mk4(unsigned a, unsigned b, unsigned c, unsigned d){
  union{ unsigned u[4]; bf16x8 v; } x;
  x.u[0]=a; x.u[1]=b; x.u[2]=c; x.u[3]=d; return x.v;
}
DI f32x16 mfma32(bf16x8 a, bf16x8 b, f32x16 c){
  return __builtin_amdgcn_mfma_f32_32x32x16_bf16(a, b, c, 0, 0, 0);
}
#define MFMA16(a,b,c) __builtin_amdgcn_mfma_f32_16x16x32_bf16(a,b,c,0,0,0)
DI void gld16(const void* g, void* l){
  __builtin_amdgcn_global_load_lds(
      (const __attribute__((address_space(1))) unsigned int*)g,
      (__attribute__((address_space(3))) unsigned int*)l, 16, 0, 0);
}

// ---- transpose fp32 [R][C] -> bf16 [C][R(padded ostride)] with swizzled k-units ----
// MODE 0 (proj BK=32 kernel): unit(8) pos = u ^ ((outrow>>1)&3) in 32-elem groups
// MODE 1 (8-phase GEMM / attn V^T): unit pos = u ^ (outrow&7) in 64-elem groups
template<int MODE>
__global__ __launch_bounds__(256) void transpose_k(
    const float* __restrict__ in, unsigned short* __restrict__ out,
    int R, int C, int ostride, size_t oplane){
  __shared__ unsigned short tile[32][33];
  in  += (size_t)blockIdx.z * R * C;
  out += (size_t)blockIdx.z * oplane;
  int r0 = blockIdx.y * 32, c0 = blockIdx.x * 32;
  int tx = threadIdx.x & 31, ty = threadIdx.x >> 5;
#pragma unroll
  for(int i=0;i<4;i++){
    int r = r0 + ty + i*8;
    tile[ty + i*8][tx] = f2bf(in[(size_t)r * C + c0 + tx]);
  }
  __syncthreads();
#pragma unroll
  for(int i=0;i<4;i++){
    int c = c0 + ty + i*8;     // out row
    int k = r0 + tx;           // out col (logical)
    int kp;
    if constexpr (MODE == 0)
      kp = (k & ~24) | ((((k>>3)&3) ^ ((c>>1)&3)) << 3);
    else
      kp = (k & ~56) | ((((k>>3)&7) ^ (c&7)) << 3);
    out[(size_t)c * ostride + kp] = tile[tx][ty + i*8];
  }
}

// ---- x fp32 -> bf16 with 8-phase GEMM A swizzle (8-unit, row&7), padded stride ----
__global__ __launch_bounds__(256) void xconv_k(
    const float4* __restrict__ x4, unsigned short* __restrict__ xbf){
  int idx = blockIdx.x * 256 + threadIdx.x;   // 2048*2048/4 threads
  int m = idx >> 9;
  int c4 = (idx & 511) * 4;
  float4 v = x4[idx];
  int cp = ((((c4>>3) ^ (m&7)) << 3)) | (c4 & 7);
  uint2 p; p.x = pk2(v.x, v.y); p.y = pk2(v.z, v.w);
  *(uint2*)(xbf + (size_t)m * LDP + cp) = p;
}

// ---- copy KV cache into fp32 outputs + swizzled bf16 K ----
__global__ __launch_bounds__(256) void cache_copy(
    const float4* __restrict__ ck, const float4* __restrict__ cv,
    float4* __restrict__ ok, float4* __restrict__ ov,
    unsigned short* __restrict__ Kws){
  int idx = blockIdx.x * 256 + threadIdx.x;
  const int per = TC * Dd / 4;                 // 32768 per (b,h)
  int bh = idx / per, r = idx - bh * per;
  int dst = bh * (CTX * Dd / 4) + r;
  float4 kv = ck[idx];
  ok[dst] = kv;
  ov[dst] = cv[idx];
  int key = r >> 5, dq = (r & 31) * 4;
  int dp = (((dq>>3) ^ (key&7)) << 3) | (dq & 7);
  uint2 p; p.x = pk2(kv.x, kv.y); p.y = pk2(kv.z, kv.w);
  *(uint2*)(Kws + ((size_t)bh * CTX + key) * Dd + dp) = p;
}

// ================= 256x256 8-phase GEMM (QKV) =================
// C[m][n] = sum_k A[m][k]*W[k][n]; A, BT bf16 with u^=(row&7) unit swizzle, stride LDP.
// M=2048 N=6144 K=2048. Grid 192 (8 m x 24 n), 512 threads, 128KiB LDS.
__global__ __launch_bounds__(512) void gemm8_k(
    const unsigned short* __restrict__ A, const unsigned short* __restrict__ BT,
    unsigned short* __restrict__ q_ws, float* __restrict__ out_k,
    float* __restrict__ out_v, unsigned short* __restrict__ Kws){
  __shared__ unsigned short lds[65536];        // A: [0,32768) B: [32768,65536)
  int tid = threadIdx.x, lane = tid & 63, w = tid >> 6;
  int lr = lane & 15, lg = lane >> 4;
  int wm = w >> 2, wn = w & 3;
  int bid = blockIdx.x;                        // 192 blocks, 192%8==0
  int swz = (bid & 7) * 24 + (bid >> 3);       // bijective XCD swizzle
  int m0 = (swz & 7) * 256;
  int n0 = (swz >> 3) * 256;

  int r8 = lane >> 3, c8 = (lane & 7) * 8;
  const unsigned short* Asrc = A  + (size_t)(m0 + w*16 + r8)*LDP + c8;
  const unsigned short* Bsrc = BT + (size_t)(n0 + w*16 + r8)*LDP + c8;
  unsigned short* ldsA = lds;
  unsigned short* ldsB = lds + 32768;

  auto stgA = [&](int b, int h, int kt){
    const unsigned short* s = Asrc + (size_t)(h*128)*LDP + kt*64;
    unsigned short* d = ldsA + b*16384 + h*8192 + w*1024;
    gld16(s, d);
    gld16(s + (size_t)8*LDP, d + 512);
  };
  auto stgB = [&](int b, int h, int kt){
    const unsigned short* s = Bsrc + (size_t)(h*128)*LDP + kt*64;
    unsigned short* d = ldsB + b*16384 + h*8192 + w*1024;
    gld16(s, d);
    gld16(s + (size_t)8*LDP, d + 512);
  };

  int ua0 = ( lg      ^ (lr & 7)) * 8;   // kk=0 physical unit offset (elems)
  int ua1 = ((4 + lg) ^ (lr & 7)) * 8;   // kk=1
  const unsigned short* apA = ldsA + (wm*128 + lr)*64;
  const unsigned short* apB = ldsB + (wn*64  + lr)*64;

  f32x4 acc[8][4];
#pragma unroll
  for(int i=0;i<8;i++)
#pragma unroll
    for(int j=0;j<4;j++) acc[i][j] = (f32x4){0.f,0.f,0.f,0.f};
  bf16x8 bfr[4][2];

  // prologue: K-tile0 fully + B(1); leave B(1) in flight
  stgA(0,0,0); stgA(0,1,0); stgB(0,0,0); stgB(0,1,0); stgB(1,0,1); stgB(1,1,1);
  asm volatile("s_waitcnt vmcnt(4)" ::: "memory");
  __builtin_amdgcn_s_barrier();

#define PHASE(BUF, Q, STAGE, VM)                                           \
  {                                                                        \
    const unsigned short* pa = apA + (BUF)*16384 + (Q)*2048;               \
    bf16x8 a00 = *(const bf16x8*)(pa + ua0);                               \
    bf16x8 a10 = *(const bf16x8*)(pa + 1024 + ua0);                        \
    bf16x8 a01 = *(const bf16x8*)(pa + ua1);                               \
    bf16x8 a11 = *(const bf16x8*)(pa + 1024 + ua1);                        \
    if((Q) == 0){                                                          \
      const unsigned short* pb = apB + (BUF)*16384;                        \
      _Pragma("unroll")                                                    \
      for(int ni=0;ni<4;ni++){                                             \
        bfr[ni][0] = *(const bf16x8*)(pb + ni*1024 + ua0);                 \
        bfr[ni][1] = *(const bf16x8*)(pb + ni*1024 + ua1);                 \
      }                                                                    \
    }                                                                      \
    STAGE;                                                                 \
    __builtin_amdgcn_s_barrier();                                          \
    asm volatile("s_waitcnt lgkmcnt(0)" ::: "memory");                     \
    __builtin_amdgcn_s_setprio(1);                                         \
    _Pragma("unroll")                                                      \
    for(int ni=0;ni<4;ni++){                                               \
      acc[2*(Q)][ni]   = MFMA16(a00, bfr[ni][0], acc[2*(Q)][ni]);          \
      acc[2*(Q)+1][ni] = MFMA16(a10, bfr[ni][0], acc[2*(Q)+1][ni]);        \
    }                                                                      \
    _Pragma("unroll")                                                      \
    for(int ni=0;ni<4;ni++){                                               \
      acc[2*(Q)][ni]   = MFMA16(a01, bfr[ni][1], acc[2*(Q)][ni]);          \
      acc[2*(Q)+1][ni] = MFMA16(a11, bfr[ni][1], acc[2*(Q)+1][ni]);        \
    }                                                                      \
    __builtin_amdgcn_s_setprio(0);                                         \
    VM;                                                                    \
    __builtin_amdgcn_s_barrier();                                          \
  }

#define VMW asm volatile("s_waitcnt vmcnt(4)" ::: "memory")

#pragma unroll 1
  for(int i=0;i<16;i++){
    int t1 = 2*i+1, t2 = (2*i+2)&31, t3 = (2*i+3)&31;
    PHASE(0, 0, stgA(1,0,t1), );
    PHASE(0, 1, stgA(1,1,t1), );
    PHASE(0, 2, stgB(0,0,t2), );
    PHASE(0, 3, stgB(0,1,t2), VMW);
    PHASE(1, 0, stgA(0,0,t2), );
    PHASE(1, 1, stgA(0,1,t2), );
    PHASE(1, 2, stgB(1,0,t3), );
    PHASE(1, 3, stgB(1,1,t3), VMW);
  }
#undef PHASE
#undef VMW
  asm volatile("s_waitcnt vmcnt(0)" ::: "memory");

  // epilogue: QKV scatter
#pragma unroll
  for(int mi=0;mi<8;mi++){
#pragma unroll
    for(int ni=0;ni<4;ni++){
      int n = n0 + wn*64 + ni*16 + lr;
      int seg = n >> 11;
      int h = (n >> 7) & 15, d = n & 127;
#pragma unroll
      for(int r=0;r<4;r++){
        int mrow = m0 + wm*128 + mi*16 + lg*4 + r;
        float v = acc[mi][ni][r];
        int b = mrow >> 10, t = mrow & 1023;
        if(seg == 0){
          q_ws[((size_t)(b*Hh + h)*Tt + t)*Dd + d] = f2bf(v * QSCALE);
        } else if(seg == 1){
          int key = TC + t;
          size_t base = (size_t)(b*Hh + h)*CTX + key;
          out_k[base*Dd + d] = v;
          int dp = (((d>>3) ^ (key&7)) << 3) | (d & 7);
          Kws[base*Dd + dp] = f2bf(v);
        } else {
          out_v[((size_t)(b*Hh + h)*CTX + TC + t)*Dd + d] = v;
        }
      }
    }
  }
}

// ---- 128x128 BK=32 GEMM (proj): A, BT bf16 MODE-0 swizzled, stride LDP ----
__global__ __launch_bounds__(256) void gemmp_k(
    const unsigned short* __restrict__ A, const unsigned short* __restrict__ BT,
    const float* __restrict__ bias, float* __restrict__ outp){
  constexpr int K = 2048;
  __shared__ unsigned short Al[2][128*32];
  __shared__ unsigned short Bl[2][128*32];
  int tid = threadIdx.x, lane = tid & 63, w = tid >> 6;
  int lr = lane & 15, lg = lane >> 4;
  int m0 = blockIdx.x * 128, n0 = blockIdx.y * 128;
  int wr = (w >> 1) * 64, wc = (w & 1) * 64;
  int swz = (lg ^ ((lr >> 1) & 3)) << 3;

  f32x4 acc[4][4];
#pragma unroll
  for(int i=0;i<4;i++)
#pragma unroll
    for(int j=0;j<4;j++) acc[i][j] = (f32x4){0.f,0.f,0.f,0.f};

  auto stage = [&](int buf, int k0){
#pragma unroll
    for(int li=0; li<2; li++){
      int rb = w*32 + li*16;
      gld16(A  + (size_t)(m0 + rb + (lane>>2))*LDP + k0 + (lane&3)*8, &Al[buf][rb*32]);
      gld16(BT + (size_t)(n0 + rb + (lane>>2))*LDP + k0 + (lane&3)*8, &Bl[buf][rb*32]);
    }
  };
  stage(0, 0);
  __syncthreads();
  int buf = 0;
  for(int k0 = 0; k0 < K; k0 += 32){
    if(k0 + 32 < K) stage(buf^1, k0 + 32);
    bf16x8 af[4], bfr[4];
#pragma unroll
    for(int mi=0;mi<4;mi++) af[mi]  = *(const bf16x8*)&Al[buf][(wr+mi*16+lr)*32 + swz];
#pragma unroll
    for(int ni=0;ni<4;ni++) bfr[ni] = *(const bf16x8*)&Bl[buf][(wc+ni*16+lr)*32 + swz];
#pragma unroll
    for(int mi=0;mi<4;mi++)
#pragma unroll
      for(int ni=0;ni<4;ni++)
        acc[mi][ni] = MFMA16(af[mi], bfr[ni], acc[mi][ni]);
    __syncthreads();
    buf ^= 1;
  }

#pragma unroll
  for(int mi=0;mi<4;mi++){
#pragma unroll
    for(int ni=0;ni<4;ni++){
      int n = n0 + wc + ni*16 + lr;
#pragma unroll
      for(int r=0;r<4;r++){
        int mrow = m0 + wr + mi*16 + lg*4 + r;
        outp[(size_t)mrow * Cc + n] = acc[mi][ni][r] + bias[n];
      }
    }
  }
}

// ---- flash attention, swapped-QK 32x32, 4 waves x 32q, key-split x2 ----
__global__ __launch_bounds__(256, 2) void attn_k(
    const unsigned short* __restrict__ q_ws,
    const unsigned short* __restrict__ Kws,
    const unsigned short* __restrict__ Vt,
    float* __restrict__ O0, unsigned short* __restrict__ O1b,
    float* __restrict__ ml){
  __shared__ unsigned short Kl[2][64*128];   // [key][128] swizzled
  __shared__ unsigned short Vl[2][128*64];   // [d][64]  swizzled
  int tid = threadIdx.x, lane = tid & 63, w = tid >> 6;
  int l31 = lane & 31, hi = lane >> 5, r7 = l31 & 7;
  int qt = blockIdx.x, split = blockIdx.y, bh = blockIdx.z;
  int q0b = qt * 128, qw0 = q0b + w * 32;
  const unsigned short* Kb = Kws + (size_t)bh * CTX * Dd;
  const unsigned short* Vb = Vt  + (size_t)bh * Dd * VS;

  const unsigned short* qp = q_ws + ((size_t)bh * Tt + qw0 + l31) * Dd + hi * 8;
  bf16x8 qf[8];
#pragma unroll
  for(int ks=0;ks<8;ks++) qf[ks] = *(const bf16x8*)(qp + ks*16);

  f32x16 o[4];
#pragma unroll
  for(int dt=0;dt<4;dt++)
#pragma unroll
    for(int r=0;r<16;r++) o[dt][r] = 0.f;
  float m = -3e38f, l = 0.f;

  int nts = ((TC + q0b + 128) >> 6) >> 1;   // tiles for this split

  auto stageK = [&](int buf, int j0){
#pragma unroll
    for(int li=0; li<4; li++){
      gld16(Kb + (size_t)(j0 + w*16 + li*4 + (lane>>4))*Dd + (lane&15)*8,
            &Kl[buf][(w*16 + li*4)*128]);
    }
  };
  auto stageV = [&](int buf, int j0){
#pragma unroll
    for(int li=0; li<4; li++){
      gld16(Vb + (size_t)(w*32 + li*8 + (lane>>3))*VS + j0 + (lane&7)*8,
            &Vl[buf][(w*32 + li*8)*64]);
    }
  };

  stageK(0, split*64); stageV(0, split*64);
  __syncthreads();
  int buf = 0;
#pragma unroll 1
  for(int t = 0; t < nts; t++){
    int j0 = (2*t + split) * 64;
    if(t + 1 < nts){ stageK(buf^1, j0 + 128); stageV(buf^1, j0 + 128); }

    if(j0 <= TC + qw0 + 31){
      f32x16 s0, s1;
#pragma unroll
      for(int r=0;r<16;r++){ s0[r] = 0.f; s1[r] = 0.f; }
#pragma unroll
      for(int ks=0; ks<8; ks++){
        int ub = ((ks*2 + hi) ^ r7) << 3;
        bf16x8 kf0 = *(const bf16x8*)&Kl[buf][l31*128 + ub];
        bf16x8 kf1 = *(const bf16x8*)&Kl[buf][(32+l31)*128 + ub];
        s0 = mfma32(kf0, qf[ks], s0);
        s1 = mfma32(kf1, qf[ks], s1);
      }
      int qabs = TC + qw0 + l31;
      if(j0 + 63 > TC + qw0){
#pragma unroll
        for(int r=0;r<16;r++){
          int kk = (r&3) + 8*(r>>2) + 4*hi;
          if(j0 + kk > qabs)      s0[r] = -1e30f;
          if(j0 + 32 + kk > qabs) s1[r] = -1e30f;
        }
      }
      float tm = fmaxf(s0[0], s1[0]);
#pragma unroll
      for(int r=1;r<16;r++) tm = fmaxf(tm, fmaxf(s0[r], s1[r]));
      tm = fmaxf(tm, __shfl_xor(tm, 32, 64));
      if(!__all(tm - m <= 8.f)){
        float mn = fmaxf(m, tm);
        float alpha = __expf(m - mn);
        m = mn;
        l *= alpha;
        float ar[16];
#pragma unroll
        for(int r=0;r<16;r++){
          int kk = (r&3) + 8*(r>>2) + 4*hi;
          ar[r] = __shfl(alpha, kk, 64);
        }
#pragma unroll
        for(int dt=0;dt<4;dt++)
#pragma unroll
          for(int r=0;r<16;r++) o[dt][r] *= ar[r];
      }
#pragma unroll
      for(int r=0;r<16;r++){ s0[r] = __expf(s0[r] - m); s1[r] = __expf(s1[r] - m); }
      float ts = 0.f;
#pragma unroll
      for(int r=0;r<16;r++) ts += s0[r] + s1[r];
      ts += __shfl_xor(ts, 32, 64);
      l += ts;
#pragma unroll
      for(int ks16=0; ks16<4; ks16++){
        f32x16 p = (ks16 & 2) ? s1 : s0;
        int fb = (ks16 & 1) * 8;
        unsigned e0 = pk2(p[fb+0], p[fb+1]);
        unsigned e1 = pk2(p[fb+2], p[fb+3]);
        unsigned e2 = pk2(p[fb+4], p[fb+5]);
        unsigned e3 = pk2(p[fb+6], p[fb+7]);
        unsigned x0 = __shfl_xor(e0, 32, 64);
        unsigned x1 = __shfl_xor(e1, 32, 64);
        unsigned x2 = __shfl_xor(e2, 32, 64);
        unsigned x3 = __shfl_xor(e3, 32, 64);
        bf16x8 pa = mk4(hi ? x2 : e0, hi ? x3 : e1, hi ? e2 : x0, hi ? e3 : x1);
        int ub = ((ks16*2 + hi) ^ r7) << 3;
#pragma unroll
        for(int dt=0; dt<4; dt++){
          bf16x8 vf = *(const bf16x8*)&Vl[buf][(dt*32 + l31)*64 + ub];
          o[dt] = mfma32(pa, vf, o[dt]);
        }
      }
    }
    __syncthreads();
    buf ^= 1;
  }

  if(split == 0){
#pragma unroll
    for(int dt=0; dt<4; dt++)
#pragma unroll
      for(int r=0; r<16; r++){
        int q = qw0 + (r&3) + 8*(r>>2) + 4*hi;
        O0[((size_t)bh*Tt + q)*Dd + dt*32 + l31] = o[dt][r];
      }
  } else {
#pragma unroll
    for(int dt=0; dt<4; dt++)
#pragma unroll
      for(int r=0; r<16; r++){
        int q = qw0 + (r&3) + 8*(r>>2) + 4*hi;
        O1b[((size_t)bh*Tt + q)*Dd + dt*32 + l31] = f2bf(o[dt][r]);
      }
  }
  if(lane < 32){
    float* mlp = ml + (((size_t)split*32 + bh)*Tt + qw0 + l31)*2;
    mlp[0] = m; mlp[1] = l;
  }
}

// ---- combine split partials -> bf16 attn_ws (MODE-0 swizzle, stride LDP) ----
__global__ __launch_bounds__(256) void combine_k(
    const float* __restrict__ O0, const unsigned short* __restrict__ O1b,
    const float* __restrict__ ml, unsigned short* __restrict__ attn_ws){
  int tid = threadIdx.x;
  int d = tid & 127, rl = tid >> 7;
  int row = blockIdx.x * 2 + rl;          // bh*1024 + t
  int bh = row >> 10, t = row & 1023;
  const float* p0 = ml + ((size_t)bh * Tt + t) * 2;
  const float* p1 = ml + (((size_t)32 + bh) * Tt + t) * 2;
  float m0 = p0[0], l0 = p0[1], m1 = p1[0], l1 = p1[1];
  float M = fmaxf(m0, m1);
  float e0 = __expf(m0 - M), e1 = __expf(m1 - M);
  float inv = 1.f / (l0*e0 + l1*e1);
  size_t off = (size_t)row * Dd + d;
  float v = (O0[off]*e0 + bf2f(O1b[off])*e1) * inv;
  int b = bh >> 4, h = bh & 15;
  int mrow = b * Tt + t;
  int c = h * Dd + d;
  int cp = (c & ~24) | ((((c>>3)&3) ^ ((mrow>>1)&3)) << 3);
  attn_ws[(size_t)mrow * LDP + cp] = f2bf(v);
}

extern "C" void kernel_launch(void* const* d_in, const int* in_sizes, int n_in,
                              void* d_out, int out_size, void* d_ws, size_t ws_size,
                              hipStream_t stream){
  const float* x       = (const float*)d_in[0];
  const float* cache_k = (const float*)d_in[1];
  const float* cache_v = (const float*)d_in[2];
  const float* W_qkv   = (const float*)d_in[3];
  const float* W_proj  = (const float*)d_in[4];
  const float* b_proj  = (const float*)d_in[5];

  float* out   = (float*)d_out;
  float* out_k = out   + (size_t)Bb*Tt*Cc;
  float* out_v = out_k + (size_t)Bb*Hh*CTX*Dd;

  if(ws_size < (size_t)67108864) return;  // need 64 MiB scratch
  char* ws = (char*)d_ws;
  // liveness-packed layout (timeline: tWq,xconv,ccopy,gemm8,tV,attn,tWp,combine,gemmp)
  unsigned short* WqkvT  = (unsigned short*)(ws);              // [0,25952256) 6144x2112
  unsigned short* Vt_ws  = (unsigned short*)(ws);              // [0,17039360) after gemm8
  unsigned short* attn_ws= (unsigned short*)(ws);              // [0,8650752) after attn
  unsigned short* WprojT = (unsigned short*)(ws + 17039360);   // [17039360,25690112)
  unsigned short* Kws    = (unsigned short*)(ws + 25952256);   // [25952256,42729472)
  unsigned short* q_ws   = (unsigned short*)(ws + 42729472);   // [42729472,51118080)
  unsigned short* x_bf   = (unsigned short*)(ws + 51118080);   // [51118080,59768832)
  unsigned short* O1b    = (unsigned short*)(ws + 51118080);   // after gemm8 (attn out)
  float*          ml     = (float*)(ws + 59768832);            // [59768832,60293120)
  float*          O0     = out;                                // out slot as scratch

  transpose_k<1><<<dim3(192,64,1), 256, 0, stream>>>(W_qkv, WqkvT, 2048, 6144,
                                                     LDP, (size_t)6144*LDP);
  xconv_k<<<dim3(4096), 256, 0, stream>>>((const float4*)x, x_bf);
  cache_copy<<<dim3(4096), 256, 0, stream>>>((const float4*)cache_k, (const float4*)cache_v,
                                             (float4*)out_k, (float4*)out_v, Kws);
  gemm8_k<<<dim3(192), 512, 0, stream>>>(x_bf, WqkvT, q_ws, out_k, out_v, Kws);
  transpose_k<1><<<dim3(4,64,32), 256, 0, stream>>>(out_v, Vt_ws, 2048, 128,
                                                    VS, (size_t)128*VS);
  attn_k<<<dim3(8,2,32), 256, 0, stream>>>(q_ws, Kws, Vt_ws, O0, O1b, ml);
  transpose_k<0><<<dim3(64,64,1), 256, 0, stream>>>(W_proj, WprojT, 2048, 2048,
                                                    LDP, (size_t)2048*LDP);
  combine_k<<<dim3(16384), 256, 0, stream>>>(O0, O1b, ml, attn_ws);
  gemmp_k<<<dim3(16,16), 256, 0, stream>>>(attn_ws, WprojT, b_proj, out);
}

// Round 5
// 214.320 us; speedup vs baseline: 1.4521x; 1.0244x over previous
//
#include <hip/hip_runtime.h>
#include <hip/hip_bf16.h>

typedef __attribute__((ext_vector_type(8))) short bf16x8;
typedef __attribute__((ext_vector_type(4))) float f32x4;
typedef __attribute__((ext_vector_type(16))) float f32x16;

#define DI __device__ __forceinline__

static constexpr int Bb  = 2;
static constexpr int Tt  = 1024;
static constexpr int Cc  = 2048;
static constexpr int Hh  = 16;
static constexpr int Dd  = 128;
static constexpr int TC  = 1024;   // cached tokens (seq_start)
static constexpr int CTX = 2048;   // total context
static constexpr int LDP = 2112;   // padded row stride for GEMM operands
static constexpr int VS  = 2080;   // padded Vt row stride
static constexpr float QSCALE = 0.08838834764831845f; // 1/sqrt(128)

DI unsigned short f2bf(float f){
  unsigned u = __builtin_bit_cast(unsigned, f);
  u += 0x7FFFu + ((u >> 16) & 1u);
  return (unsigned short)(u >> 16);
}
DI float bf2f(unsigned short s){
  return __builtin_bit_cast(float, (unsigned)s << 16);
}
DI unsigned pk2(float a, float b){
  return (unsigned)f2bf(a) | ((unsigned)f2bf(b) << 16);
}
DI bf16x8 mk4(unsigned a, unsigned b, unsigned c, unsigned d){
  union{ unsigned u[4]; bf16x8 v; } x;
  x.u[0]=a; x.u[1]=b; x.u[2]=c; x.u[3]=d; return x.v;
}
DI f32x16 mfma32(bf16x8 a, bf16x8 b, f32x16 c){
  return __builtin_amdgcn_mfma_f32_32x32x16_bf16(a, b, c, 0, 0, 0);
}
#define MFMA16(a,b,c) __builtin_amdgcn_mfma_f32_16x16x32_bf16(a,b,c,0,0,0)
DI void gld16(const void* g, void* l){
  __builtin_amdgcn_global_load_lds(
      (const __attribute__((address_space(1))) unsigned int*)g,
      (__attribute__((address_space(3))) unsigned int*)l, 16, 0, 0);
}
DI unsigned ldsoff(const void* p){
  return (unsigned)(size_t)(const __attribute__((address_space(3))) void*)p;
}
// inline-asm LDS read: compiler-invisible (manual lgkmcnt + sched_barrier required)
template<int OFF>
DI bf16x8 dsr(unsigned addr){
  bf16x8 v;
  if constexpr (OFF == 0)
    asm volatile("ds_read_b128 %0, %1" : "=v"(v) : "v"(addr));
  else
    asm volatile("ds_read_b128 %0, %1 offset:%2" : "=v"(v) : "v"(addr), "i"(OFF));
  return v;
}

// ---- transpose fp32 [R][C] -> bf16 [C][R(padded ostride)] with swizzled k-units ----
template<int MODE>
__global__ __launch_bounds__(256) void transpose_k(
    const float* __restrict__ in, unsigned short* __restrict__ out,
    int R, int C, int ostride, size_t oplane){
  __shared__ unsigned short tile[32][33];
  in  += (size_t)blockIdx.z * R * C;
  out += (size_t)blockIdx.z * oplane;
  int r0 = blockIdx.y * 32, c0 = blockIdx.x * 32;
  int tx = threadIdx.x & 31, ty = threadIdx.x >> 5;
#pragma unroll
  for(int i=0;i<4;i++){
    int r = r0 + ty + i*8;
    tile[ty + i*8][tx] = f2bf(in[(size_t)r * C + c0 + tx]);
  }
  __syncthreads();
#pragma unroll
  for(int i=0;i<4;i++){
    int c = c0 + ty + i*8;     // out row
    int k = r0 + tx;           // out col (logical)
    int kp;
    if constexpr (MODE == 0)
      kp = (k & ~24) | ((((k>>3)&3) ^ ((c>>1)&3)) << 3);
    else
      kp = (k & ~56) | ((((k>>3)&7) ^ (c&7)) << 3);
    out[(size_t)c * ostride + kp] = tile[tx][ty + i*8];
  }
}

// ---- x fp32 -> bf16 with 8-phase GEMM A swizzle (8-unit, row&7), padded stride ----
__global__ __launch_bounds__(256) void xconv_k(
    const float4* __restrict__ x4, unsigned short* __restrict__ xbf){
  int idx = blockIdx.x * 256 + threadIdx.x;   // 2048*2048/4 threads
  int m = idx >> 9;
  int c4 = (idx & 511) * 4;
  float4 v = x4[idx];
  int cp = ((((c4>>3) ^ (m&7)) << 3)) | (c4 & 7);
  uint2 p; p.x = pk2(v.x, v.y); p.y = pk2(v.z, v.w);
  *(uint2*)(xbf + (size_t)m * LDP + cp) = p;
}

// ---- copy KV cache into fp32 outputs + swizzled bf16 K ----
__global__ __launch_bounds__(256) void cache_copy(
    const float4* __restrict__ ck, const float4* __restrict__ cv,
    float4* __restrict__ ok, float4* __restrict__ ov,
    unsigned short* __restrict__ Kws){
  int idx = blockIdx.x * 256 + threadIdx.x;
  const int per = TC * Dd / 4;                 // 32768 per (b,h)
  int bh = idx / per, r = idx - bh * per;
  int dst = bh * (CTX * Dd / 4) + r;
  float4 kv = ck[idx];
  ok[dst] = kv;
  ov[dst] = cv[idx];
  int key = r >> 5, dq = (r & 31) * 4;
  int dp = (((dq>>3) ^ (key&7)) << 3) | (dq & 7);
  uint2 p; p.x = pk2(kv.x, kv.y); p.y = pk2(kv.z, kv.w);
  *(uint2*)(Kws + ((size_t)bh * CTX + key) * Dd + dp) = p;
}

// ================= 256x256 8-phase GEMM (QKV) =================
__global__ __launch_bounds__(512) void gemm8_k(
    const unsigned short* __restrict__ A, const unsigned short* __restrict__ BT,
    unsigned short* __restrict__ q_ws, float* __restrict__ out_k,
    float* __restrict__ out_v, unsigned short* __restrict__ Kws){
  __shared__ unsigned short lds[65536];        // A: [0,32768) B: [32768,65536) elems
  int tid = threadIdx.x, lane = tid & 63, w = tid >> 6;
  int lr = lane & 15, lg = lane >> 4;
  int wm = w >> 2, wn = w & 3;
  int bid = blockIdx.x;                        // 192 blocks, 192%8==0
  int swz = (bid & 7) * 24 + (bid >> 3);       // bijective XCD swizzle
  int m0 = (swz & 7) * 256;
  int n0 = (swz >> 3) * 256;

  int r8 = lane >> 3, c8 = (lane & 7) * 8;
  const unsigned short* Asrc = A  + (size_t)(m0 + w*16 + r8)*LDP + c8;
  const unsigned short* Bsrc = BT + (size_t)(n0 + w*16 + r8)*LDP + c8;
  unsigned short* ldsA = lds;
  unsigned short* ldsB = lds + 32768;

  auto stgA = [&](int b, int h, int kt){
    const unsigned short* s = Asrc + (size_t)(h*128)*LDP + kt*64;
    unsigned short* d = ldsA + b*16384 + h*8192 + w*1024;
    gld16(s, d);
    gld16(s + (size_t)8*LDP, d + 512);
  };
  auto stgB = [&](int b, int h, int kt){
    const unsigned short* s = Bsrc + (size_t)(h*128)*LDP + kt*64;
    unsigned short* d = ldsB + b*16384 + h*8192 + w*1024;
    gld16(s, d);
    gld16(s + (size_t)8*LDP, d + 512);
  };

  // byte addresses for asm ds_read
  unsigned LB   = ldsoff(lds);
  unsigned apAb = LB + (unsigned)(wm*128 + lr)*128;            // A row base (bytes)
  unsigned apBb = LB + 65536u + (unsigned)(wn*64 + lr)*128;    // B row base (bytes)
  unsigned ua0b = (unsigned)(( lg      ^ (lr & 7)) * 16);      // kk=0 unit (bytes)
  unsigned ua1b = (unsigned)(((4 + lg) ^ (lr & 7)) * 16);      // kk=1 unit (bytes)

  f32x4 acc[8][4];
#pragma unroll
  for(int i=0;i<8;i++)
#pragma unroll
    for(int j=0;j<4;j++) acc[i][j] = (f32x4){0.f,0.f,0.f,0.f};
  bf16x8 bfr[4][2];

  // prologue: K-tile0 fully + B(1); leave B(1) in flight
  stgA(0,0,0); stgA(0,1,0); stgB(0,0,0); stgB(0,1,0); stgB(1,0,1); stgB(1,1,1);
  asm volatile("s_waitcnt vmcnt(4)" ::: "memory");
  __builtin_amdgcn_s_barrier();

#define PHASE(BUF, Q, STAGE, VM)                                           \
  {                                                                        \
    unsigned a0 = apAb + (BUF)*32768u + (Q)*4096u + ua0b;                  \
    unsigned a1 = apAb + (BUF)*32768u + (Q)*4096u + ua1b;                  \
    bf16x8 a00 = dsr<0>(a0);                                               \
    bf16x8 a10 = dsr<2048>(a0);                                            \
    bf16x8 a01 = dsr<0>(a1);                                               \
    bf16x8 a11 = dsr<2048>(a1);                                            \
    if((Q) == 0){                                                          \
      unsigned b0 = apBb + (BUF)*32768u + ua0b;                            \
      unsigned b1 = apBb + (BUF)*32768u + ua1b;                            \
      bfr[0][0] = dsr<0>(b0);    bfr[1][0] = dsr<2048>(b0);                \
      bfr[2][0] = dsr<4096>(b0); bfr[3][0] = dsr<6144>(b0);                \
      bfr[0][1] = dsr<0>(b1);    bfr[1][1] = dsr<2048>(b1);                \
      bfr[2][1] = dsr<4096>(b1); bfr[3][1] = dsr<6144>(b1);                \
    }                                                                      \
    STAGE;                                                                 \
    __builtin_amdgcn_s_barrier();                                          \
    asm volatile("s_waitcnt lgkmcnt(0)" ::: "memory");                     \
    __builtin_amdgcn_sched_barrier(0);                                     \
    __builtin_amdgcn_s_setprio(1);                                         \
    _Pragma("unroll")                                                      \
    for(int ni=0;ni<4;ni++){                                               \
      acc[2*(Q)][ni]   = MFMA16(a00, bfr[ni][0], acc[2*(Q)][ni]);          \
      acc[2*(Q)+1][ni] = MFMA16(a10, bfr[ni][0], acc[2*(Q)+1][ni]);        \
    }                                                                      \
    _Pragma("unroll")                                                      \
    for(int ni=0;ni<4;ni++){                                               \
      acc[2*(Q)][ni]   = MFMA16(a01, bfr[ni][1], acc[2*(Q)][ni]);          \
      acc[2*(Q)+1][ni] = MFMA16(a11, bfr[ni][1], acc[2*(Q)+1][ni]);        \
    }                                                                      \
    __builtin_amdgcn_s_setprio(0);                                         \
    VM;                                                                    \
    __builtin_amdgcn_s_barrier();                                          \
  }

#define VMW asm volatile("s_waitcnt vmcnt(4)" ::: "memory")

#pragma unroll 1
  for(int i=0;i<16;i++){
    int t1 = 2*i+1, t2 = (2*i+2)&31, t3 = (2*i+3)&31;
    PHASE(0, 0, stgA(1,0,t1), );
    PHASE(0, 1, stgA(1,1,t1), );
    PHASE(0, 2, stgB(0,0,t2), );
    PHASE(0, 3, stgB(0,1,t2), VMW);
    PHASE(1, 0, stgA(0,0,t2), );
    PHASE(1, 1, stgA(0,1,t2), );
    PHASE(1, 2, stgB(1,0,t3), );
    PHASE(1, 3, stgB(1,1,t3), VMW);
  }
#undef PHASE
#undef VMW
  asm volatile("s_waitcnt vmcnt(0)" ::: "memory");

  // epilogue: QKV scatter
#pragma unroll
  for(int mi=0;mi<8;mi++){
#pragma unroll
    for(int ni=0;ni<4;ni++){
      int n = n0 + wn*64 + ni*16 + lr;
      int seg = n >> 11;
      int h = (n >> 7) & 15, d = n & 127;
#pragma unroll
      for(int r=0;r<4;r++){
        int mrow = m0 + wm*128 + mi*16 + lg*4 + r;
        float v = acc[mi][ni][r];
        int b = mrow >> 10, t = mrow & 1023;
        if(seg == 0){
          q_ws[((size_t)(b*Hh + h)*Tt + t)*Dd + d] = f2bf(v * QSCALE);
        } else if(seg == 1){
          int key = TC + t;
          size_t base = (size_t)(b*Hh + h)*CTX + key;
          out_k[base*Dd + d] = v;
          int dp = (((d>>3) ^ (key&7)) << 3) | (d & 7);
          Kws[base*Dd + dp] = f2bf(v);
        } else {
          out_v[((size_t)(b*Hh + h)*CTX + TC + t)*Dd + d] = v;
        }
      }
    }
  }
}

// ---- 128x128 BK=32 GEMM (proj): A, BT bf16 MODE-0 swizzled, stride LDP ----
__global__ __launch_bounds__(256) void gemmp_k(
    const unsigned short* __restrict__ A, const unsigned short* __restrict__ BT,
    const float* __restrict__ bias, float* __restrict__ outp){
  constexpr int K = 2048;
  __shared__ unsigned short Al[2][128*32];
  __shared__ unsigned short Bl[2][128*32];
  int tid = threadIdx.x, lane = tid & 63, w = tid >> 6;
  int lr = lane & 15, lg = lane >> 4;
  int m0 = blockIdx.x * 128, n0 = blockIdx.y * 128;
  int wr = (w >> 1) * 64, wc = (w & 1) * 64;
  int swz = (lg ^ ((lr >> 1) & 3)) << 3;

  unsigned baseAb = ldsoff(Al) + (unsigned)(((wr + lr)*32 + swz)*2);
  unsigned baseBb = ldsoff(Bl) + (unsigned)(((wc + lr)*32 + swz)*2);

  f32x4 acc[4][4];
#pragma unroll
  for(int i=0;i<4;i++)
#pragma unroll
    for(int j=0;j<4;j++) acc[i][j] = (f32x4){0.f,0.f,0.f,0.f};

  auto stage = [&](int buf, int k0){
#pragma unroll
    for(int li=0; li<2; li++){
      int rb = w*32 + li*16;
      gld16(A  + (size_t)(m0 + rb + (lane>>2))*LDP + k0 + (lane&3)*8, &Al[buf][rb*32]);
      gld16(BT + (size_t)(n0 + rb + (lane>>2))*LDP + k0 + (lane&3)*8, &Bl[buf][rb*32]);
    }
  };
  stage(0, 0);
  __syncthreads();
  int buf = 0;
  for(int k0 = 0; k0 < K; k0 += 32){
    if(k0 + 32 < K) stage(buf^1, k0 + 32);
    unsigned aA = baseAb + (unsigned)buf*8192u;
    unsigned aB = baseBb + (unsigned)buf*8192u;
    bf16x8 af[4], bfr[4];
    af[0]  = dsr<0>(aA);    af[1]  = dsr<1024>(aA);
    af[2]  = dsr<2048>(aA); af[3]  = dsr<3072>(aA);
    bfr[0] = dsr<0>(aB);    bfr[1] = dsr<1024>(aB);
    bfr[2] = dsr<2048>(aB); bfr[3] = dsr<3072>(aB);
    asm volatile("s_waitcnt lgkmcnt(0)" ::: "memory");
    __builtin_amdgcn_sched_barrier(0);
#pragma unroll
    for(int mi=0;mi<4;mi++)
#pragma unroll
      for(int ni=0;ni<4;ni++)
        acc[mi][ni] = MFMA16(af[mi], bfr[ni], acc[mi][ni]);
    __syncthreads();
    buf ^= 1;
  }

#pragma unroll
  for(int mi=0;mi<4;mi++){
#pragma unroll
    for(int ni=0;ni<4;ni++){
      int n = n0 + wc + ni*16 + lr;
#pragma unroll
      for(int r=0;r<4;r++){
        int mrow = m0 + wr + mi*16 + lg*4 + r;
        outp[(size_t)mrow * Cc + n] = acc[mi][ni][r] + bias[n];
      }
    }
  }
}

// ---- flash attention, swapped-QK 32x32, 4 waves x 32q, key-split x2 ----
__global__ __launch_bounds__(256, 2) void attn_k(
    const unsigned short* __restrict__ q_ws,
    const unsigned short* __restrict__ Kws,
    const unsigned short* __restrict__ Vt,
    float* __restrict__ O0, unsigned short* __restrict__ O1b,
    float* __restrict__ ml){
  __shared__ unsigned short Kl[2][64*128];   // [key][128] swizzled
  __shared__ unsigned short Vl[2][128*64];   // [d][64]  swizzled
  int tid = threadIdx.x, lane = tid & 63, w = tid >> 6;
  int l31 = lane & 31, hi = lane >> 5, r7 = l31 & 7;
  int qt = blockIdx.x, split = blockIdx.y, bh = blockIdx.z;
  int q0b = qt * 128, qw0 = q0b + w * 32;
  const unsigned short* Kb = Kws + (size_t)bh * CTX * Dd;
  const unsigned short* Vb = Vt  + (size_t)bh * Dd * VS;

  const unsigned short* qp = q_ws + ((size_t)bh * Tt + qw0 + l31) * Dd + hi * 8;
  bf16x8 qf[8];
#pragma unroll
  for(int ks=0;ks<8;ks++) qf[ks] = *(const bf16x8*)(qp + ks*16);

  f32x16 o[4];
#pragma unroll
  for(int dt=0;dt<4;dt++)
#pragma unroll
    for(int r=0;r<16;r++) o[dt][r] = 0.f;
  float m = -3e38f, l = 0.f;

  int nts = ((TC + q0b + 128) >> 6) >> 1;   // tiles for this split

  auto stageK = [&](int buf, int j0){
#pragma unroll
    for(int li=0; li<4; li++){
      gld16(Kb + (size_t)(j0 + w*16 + li*4 + (lane>>4))*Dd + (lane&15)*8,
            &Kl[buf][(w*16 + li*4)*128]);
    }
  };
  auto stageV = [&](int buf, int j0){
#pragma unroll
    for(int li=0; li<4; li++){
      gld16(Vb + (size_t)(w*32 + li*8 + (lane>>3))*VS + j0 + (lane&7)*8,
            &Vl[buf][(w*32 + li*8)*64]);
    }
  };

  stageK(0, split*64); stageV(0, split*64);
  __syncthreads();
  int buf = 0;
#pragma unroll 1
  for(int t = 0; t < nts; t++){
    int j0 = (2*t + split) * 64;
    if(t + 1 < nts){ stageK(buf^1, j0 + 128); stageV(buf^1, j0 + 128); }

    if(j0 <= TC + qw0 + 31){
      f32x16 s0, s1;
#pragma unroll
      for(int r=0;r<16;r++){ s0[r] = 0.f; s1[r] = 0.f; }
#pragma unroll
      for(int ks=0; ks<8; ks++){
        int ub = ((ks*2 + hi) ^ r7) << 3;
        bf16x8 kf0 = *(const bf16x8*)&Kl[buf][l31*128 + ub];
        bf16x8 kf1 = *(const bf16x8*)&Kl[buf][(32+l31)*128 + ub];
        s0 = mfma32(kf0, qf[ks], s0);
        s1 = mfma32(kf1, qf[ks], s1);
      }
      int qabs = TC + qw0 + l31;
      if(j0 + 63 > TC + qw0){
#pragma unroll
        for(int r=0;r<16;r++){
          int kk = (r&3) + 8*(r>>2) + 4*hi;
          if(j0 + kk > qabs)      s0[r] = -1e30f;
          if(j0 + 32 + kk > qabs) s1[r] = -1e30f;
        }
      }
      float tm = fmaxf(s0[0], s1[0]);
#pragma unroll
      for(int r=1;r<16;r++) tm = fmaxf(tm, fmaxf(s0[r], s1[r]));
      tm = fmaxf(tm, __shfl_xor(tm, 32, 64));
      if(!__all(tm - m <= 8.f)){
        float mn = fmaxf(m, tm);
        float alpha = __expf(m - mn);
        m = mn;
        l *= alpha;
        float ar[16];
#pragma unroll
        for(int r=0;r<16;r++){
          int kk = (r&3) + 8*(r>>2) + 4*hi;
          ar[r] = __shfl(alpha, kk, 64);
        }
#pragma unroll
        for(int dt=0;dt<4;dt++)
#pragma unroll
          for(int r=0;r<16;r++) o[dt][r] *= ar[r];
      }
#pragma unroll
      for(int r=0;r<16;r++){ s0[r] = __expf(s0[r] - m); s1[r] = __expf(s1[r] - m); }
      float ts = 0.f;
#pragma unroll
      for(int r=0;r<16;r++) ts += s0[r] + s1[r];
      ts += __shfl_xor(ts, 32, 64);
      l += ts;
#pragma unroll
      for(int ks16=0; ks16<4; ks16++){
        f32x16 p = (ks16 & 2) ? s1 : s0;
        int fb = (ks16 & 1) * 8;
        unsigned e0 = pk2(p[fb+0], p[fb+1]);
        unsigned e1 = pk2(p[fb+2], p[fb+3]);
        unsigned e2 = pk2(p[fb+4], p[fb+5]);
        unsigned e3 = pk2(p[fb+6], p[fb+7]);
        unsigned x0 = __shfl_xor(e0, 32, 64);
        unsigned x1 = __shfl_xor(e1, 32, 64);
        unsigned x2 = __shfl_xor(e2, 32, 64);
        unsigned x3 = __shfl_xor(e3, 32, 64);
        bf16x8 pa = mk4(hi ? x2 : e0, hi ? x3 : e1, hi ? e2 : x0, hi ? e3 : x1);
        int ub = ((ks16*2 + hi) ^ r7) << 3;
#pragma unroll
        for(int dt=0; dt<4; dt++){
          bf16x8 vf = *(const bf16x8*)&Vl[buf][(dt*32 + l31)*64 + ub];
          o[dt] = mfma32(pa, vf, o[dt]);
        }
      }
    }
    __syncthreads();
    buf ^= 1;
  }

  if(split == 0){
#pragma unroll
    for(int dt=0; dt<4; dt++)
#pragma unroll
      for(int r=0; r<16; r++){
        int q = qw0 + (r&3) + 8*(r>>2) + 4*hi;
        O0[((size_t)bh*Tt + q)*Dd + dt*32 + l31] = o[dt][r];
      }
  } else {
#pragma unroll
    for(int dt=0; dt<4; dt++)
#pragma unroll
      for(int r=0; r<16; r++){
        int q = qw0 + (r&3) + 8*(r>>2) + 4*hi;
        O1b[((size_t)bh*Tt + q)*Dd + dt*32 + l31] = f2bf(o[dt][r]);
      }
  }
  if(lane < 32){
    float* mlp = ml + (((size_t)split*32 + bh)*Tt + qw0 + l31)*2;
    mlp[0] = m; mlp[1] = l;
  }
}

// ---- combine split partials -> bf16 attn_ws (MODE-0 swizzle, stride LDP) ----
__global__ __launch_bounds__(256) void combine_k(
    const float* __restrict__ O0, const unsigned short* __restrict__ O1b,
    const float* __restrict__ ml, unsigned short* __restrict__ attn_ws){
  int tid = threadIdx.x;
  int d = tid & 127, rl = tid >> 7;
  int row = blockIdx.x * 2 + rl;          // bh*1024 + t
  int bh = row >> 10, t = row & 1023;
  const float* p0 = ml + ((size_t)bh * Tt + t) * 2;
  const float* p1 = ml + (((size_t)32 + bh) * Tt + t) * 2;
  float m0 = p0[0], l0 = p0[1], m1 = p1[0], l1 = p1[1];
  float M = fmaxf(m0, m1);
  float e0 = __expf(m0 - M), e1 = __expf(m1 - M);
  float inv = 1.f / (l0*e0 + l1*e1);
  size_t off = (size_t)row * Dd + d;
  float v = (O0[off]*e0 + bf2f(O1b[off])*e1) * inv;
  int b = bh >> 4, h = bh & 15;
  int mrow = b * Tt + t;
  int c = h * Dd + d;
  int cp = (c & ~24) | ((((c>>3)&3) ^ ((mrow>>1)&3)) << 3);
  attn_ws[(size_t)mrow * LDP + cp] = f2bf(v);
}

extern "C" void kernel_launch(void* const* d_in, const int* in_sizes, int n_in,
                              void* d_out, int out_size, void* d_ws, size_t ws_size,
                              hipStream_t stream){
  const float* x       = (const float*)d_in[0];
  const float* cache_k = (const float*)d_in[1];
  const float* cache_v = (const float*)d_in[2];
  const float* W_qkv   = (const float*)d_in[3];
  const float* W_proj  = (const float*)d_in[4];
  const float* b_proj  = (const float*)d_in[5];

  float* out   = (float*)d_out;
  float* out_k = out   + (size_t)Bb*Tt*Cc;
  float* out_v = out_k + (size_t)Bb*Hh*CTX*Dd;

  if(ws_size < (size_t)67108864) return;  // need 64 MiB scratch
  char* ws = (char*)d_ws;
  // liveness-packed layout (timeline: tWq,xconv,ccopy,gemm8,tV,attn,tWp,combine,gemmp)
  unsigned short* WqkvT  = (unsigned short*)(ws);              // [0,25952256) 6144x2112
  unsigned short* Vt_ws  = (unsigned short*)(ws);              // [0,17039360) after gemm8
  unsigned short* attn_ws= (unsigned short*)(ws);              // [0,8650752) after attn
  unsigned short* WprojT = (unsigned short*)(ws + 17039360);   // [17039360,25690112)
  unsigned short* Kws    = (unsigned short*)(ws + 25952256);   // [25952256,42729472)
  unsigned short* q_ws   = (unsigned short*)(ws + 42729472);   // [42729472,51118080)
  unsigned short* x_bf   = (unsigned short*)(ws + 51118080);   // [51118080,59768832)
  unsigned short* O1b    = (unsigned short*)(ws + 51118080);   // after gemm8 (attn out)
  float*          ml     = (float*)(ws + 59768832);            // [59768832,60293120)
  float*          O0     = out;                                // out slot as scratch

  transpose_k<1><<<dim3(192,64,1), 256, 0, stream>>>(W_qkv, WqkvT, 2048, 6144,
                                                     LDP, (size_t)6144*LDP);
  xconv_k<<<dim3(4096), 256, 0, stream>>>((const float4*)x, x_bf);
  cache_copy<<<dim3(4096), 256, 0, stream>>>((const float4*)cache_k, (const float4*)cache_v,
                                             (float4*)out_k, (float4*)out_v, Kws);
  gemm8_k<<<dim3(192), 512, 0, stream>>>(x_bf, WqkvT, q_ws, out_k, out_v, Kws);
  transpose_k<1><<<dim3(4,64,32), 256, 0, stream>>>(out_v, Vt_ws, 2048, 128,
                                                    VS, (size_t)128*VS);
  attn_k<<<dim3(8,2,32), 256, 0, stream>>>(q_ws, Kws, Vt_ws, O0, O1b, ml);
  transpose_k<0><<<dim3(64,64,1), 256, 0, stream>>>(W_proj, WprojT, 2048, 2048,
                                                    LDP, (size_t)2048*LDP);
  combine_k<<<dim3(16384), 256, 0, stream>>>(O0, O1b, ml, attn_ws);
  gemmp_k<<<dim3(16,16), 256, 0, stream>>>(attn_ws, WprojT, b_proj, out);
}

// Round 6
// 208.679 us; speedup vs baseline: 1.4913x; 1.0270x over previous
//
#include <hip/hip_runtime.h>
#include <hip/hip_bf16.h>

typedef __attribute__((ext_vector_type(8))) short bf16x8;
typedef __attribute__((ext_vector_type(4))) float f32x4;
typedef __attribute__((ext_vector_type(16))) float f32x16;

#define DI __device__ __forceinline__

static constexpr int Bb  = 2;
static constexpr int Tt  = 1024;
static constexpr int Cc  = 2048;
static constexpr int Hh  = 16;
static constexpr int Dd  = 128;
static constexpr int TC  = 1024;   // cached tokens (seq_start)
static constexpr int CTX = 2048;   // total context
static constexpr int LDP = 2112;   // padded row stride for GEMM operands
static constexpr int VS  = 2080;   // padded Vt row stride
static constexpr float QSCALE = 0.08838834764831845f; // 1/sqrt(128)

DI unsigned short f2bf(float f){
  unsigned u = __builtin_bit_cast(unsigned, f);
  u += 0x7FFFu + ((u >> 16) & 1u);
  return (unsigned short)(u >> 16);
}
DI float bf2f(unsigned short s){
  return __builtin_bit_cast(float, (unsigned)s << 16);
}
DI unsigned pk2(float a, float b){
  return (unsigned)f2bf(a) | ((unsigned)f2bf(b) << 16);
}
DI bf16x8 mk4(unsigned a, unsigned b, unsigned c, unsigned d){
  union{ unsigned u[4]; bf16x8 v; } x;
  x.u[0]=a; x.u[1]=b; x.u[2]=c; x.u[3]=d; return x.v;
}
DI f32x16 mfma32(bf16x8 a, bf16x8 b, f32x16 c){
  return __builtin_amdgcn_mfma_f32_32x32x16_bf16(a, b, c, 0, 0, 0);
}
#define MFMA16(a,b,c) __builtin_amdgcn_mfma_f32_16x16x32_bf16(a,b,c,0,0,0)
DI void gld16(const void* g, void* l){
  __builtin_amdgcn_global_load_lds(
      (const __attribute__((address_space(1))) unsigned int*)g,
      (__attribute__((address_space(3))) unsigned int*)l, 16, 0, 0);
}
DI unsigned ldsoff(const void* p){
  return (unsigned)(size_t)(const __attribute__((address_space(3))) void*)p;
}
// inline-asm LDS read: compiler-invisible (manual lgkmcnt + sched_barrier required)
template<int OFF>
DI bf16x8 dsr(unsigned addr){
  bf16x8 v;
  if constexpr (OFF == 0)
    asm volatile("ds_read_b128 %0, %1" : "=v"(v) : "v"(addr));
  else
    asm volatile("ds_read_b128 %0, %1 offset:%2" : "=v"(v) : "v"(addr), "i"(OFF));
  return v;
}
// raw barrier: NOT instrumented by the compiler's waitcnt pass (no implicit vmcnt drain)
#define BARRAW asm volatile("s_barrier" ::: "memory")

// ---- shared transpose body: fp32 [R][C] -> bf16 [C][ostride] swizzled ----
DI void transpose_body(const float* in, unsigned short* out,
                       int R, int C, int ostride, int r0, int c0, int mode,
                       unsigned short (*tile)[33]){
  int tx = threadIdx.x & 31, ty = threadIdx.x >> 5;
#pragma unroll
  for(int i=0;i<4;i++){
    int r = r0 + ty + i*8;
    tile[ty + i*8][tx] = f2bf(in[(size_t)r * C + c0 + tx]);
  }
  __syncthreads();
#pragma unroll
  for(int i=0;i<4;i++){
    int c = c0 + ty + i*8;     // out row
    int k = r0 + tx;           // out col (logical)
    int kp;
    if(mode == 0)
      kp = (k & ~24) | ((((k>>3)&3) ^ ((c>>1)&3)) << 3);
    else
      kp = (k & ~56) | ((((k>>3)&7) ^ (c&7)) << 3);
    out[(size_t)c * ostride + kp] = tile[tx][ty + i*8];
  }
}

// ---- fused pre-work: W_qkv transpose + x conv + cache copy ----
__global__ __launch_bounds__(256) void fused_pre_k(
    const float* __restrict__ W_qkv, unsigned short* __restrict__ WqkvT,
    const float4* __restrict__ x4, unsigned short* __restrict__ xbf,
    const float4* __restrict__ ck, const float4* __restrict__ cv,
    float4* __restrict__ ok, float4* __restrict__ ov,
    unsigned short* __restrict__ Kws){
  __shared__ unsigned short tile[32][33];
  int bid = blockIdx.x;
  if(bid < 12288){
    // W_qkv^T: R=2048, C=6144, MODE 1, ostride LDP
    int bx = bid % 192, by = bid / 192;
    transpose_body(W_qkv, WqkvT, 2048, 6144, LDP, by*32, bx*32, 1, tile);
  } else if(bid < 16384){
    int idx = (bid - 12288) * 256 + threadIdx.x;   // x: 2048*2048/4
    int m = idx >> 9;
    int c4 = (idx & 511) * 4;
    float4 v = x4[idx];
    int cp = ((((c4>>3) ^ (m&7)) << 3)) | (c4 & 7);
    uint2 p; p.x = pk2(v.x, v.y); p.y = pk2(v.z, v.w);
    *(uint2*)(xbf + (size_t)m * LDP + cp) = p;
  } else {
    int idx = (bid - 16384) * 256 + threadIdx.x;
    const int per = TC * Dd / 4;                 // 32768 per (b,h)
    int bh = idx / per, r = idx - bh * per;
    int dst = bh * (CTX * Dd / 4) + r;
    float4 kv = ck[idx];
    ok[dst] = kv;
    ov[dst] = cv[idx];
    int key = r >> 5, dq = (r & 31) * 4;
    int dp = (((dq>>3) ^ (key&7)) << 3) | (dq & 7);
    uint2 p; p.x = pk2(kv.x, kv.y); p.y = pk2(kv.z, kv.w);
    *(uint2*)(Kws + ((size_t)bh * CTX + key) * Dd + dp) = p;
  }
}

// ---- fused mid-work: V^T (per bh) + W_proj^T ----
__global__ __launch_bounds__(256) void fused_mid_k(
    const float* __restrict__ out_v, unsigned short* __restrict__ Vt_ws,
    const float* __restrict__ W_proj, unsigned short* __restrict__ WprojT){
  __shared__ unsigned short tile[32][33];
  int bid = blockIdx.x;
  if(bid < 8192){
    int z = bid >> 8, rem = bid & 255;
    int bx = rem & 3, by = rem >> 2;
    transpose_body(out_v + (size_t)z*2048*128, Vt_ws + (size_t)z*128*VS,
                   2048, 128, VS, by*32, bx*32, 1, tile);
  } else {
    int b2 = bid - 8192;
    int bx = b2 & 63, by = b2 >> 6;
    transpose_body(W_proj, WprojT, 2048, 2048, LDP, by*32, bx*32, 0, tile);
  }
}

// ================= 256x256 8-phase GEMM (QKV) =================
__global__ __launch_bounds__(512) void gemm8_k(
    const unsigned short* __restrict__ A, const unsigned short* __restrict__ BT,
    unsigned short* __restrict__ q_ws, float* __restrict__ out_k,
    float* __restrict__ out_v, unsigned short* __restrict__ Kws){
  __shared__ unsigned short lds[65536];        // A: [0,32768) B: [32768,65536) elems
  int tid = threadIdx.x, lane = tid & 63, w = tid >> 6;
  int lr = lane & 15, lg = lane >> 4;
  int wm = w >> 2, wn = w & 3;
  int bid = blockIdx.x;                        // 192 blocks, 192%8==0
  int swz = (bid & 7) * 24 + (bid >> 3);       // bijective XCD swizzle
  int m0 = (swz & 7) * 256;
  int n0 = (swz >> 3) * 256;

  int r8 = lane >> 3, c8 = (lane & 7) * 8;
  const unsigned short* Asrc = A  + (size_t)(m0 + w*16 + r8)*LDP + c8;
  const unsigned short* Bsrc = BT + (size_t)(n0 + w*16 + r8)*LDP + c8;
  unsigned short* ldsA = lds;
  unsigned short* ldsB = lds + 32768;

  auto stgA = [&](int b, int h, int kt){
    const unsigned short* s = Asrc + (size_t)(h*128)*LDP + kt*64;
    unsigned short* d = ldsA + b*16384 + h*8192 + w*1024;
    gld16(s, d);
    gld16(s + (size_t)8*LDP, d + 512);
  };
  auto stgB = [&](int b, int h, int kt){
    const unsigned short* s = Bsrc + (size_t)(h*128)*LDP + kt*64;
    unsigned short* d = ldsB + b*16384 + h*8192 + w*1024;
    gld16(s, d);
    gld16(s + (size_t)8*LDP, d + 512);
  };

  // byte addresses for asm ds_read
  unsigned LB   = ldsoff(lds);
  unsigned apAb = LB + (unsigned)(wm*128 + lr)*128;            // A row base (bytes)
  unsigned apBb = LB + 65536u + (unsigned)(wn*64 + lr)*128;    // B row base (bytes)
  unsigned ua0b = (unsigned)(( lg      ^ (lr & 7)) * 16);      // kk=0 unit (bytes)
  unsigned ua1b = (unsigned)(((4 + lg) ^ (lr & 7)) * 16);      // kk=1 unit (bytes)

  f32x4 acc[8][4];
#pragma unroll
  for(int i=0;i<8;i++)
#pragma unroll
    for(int j=0;j<4;j++) acc[i][j] = (f32x4){0.f,0.f,0.f,0.f};
  bf16x8 bfr[4][2];

  // prologue: K-tile0 fully + B(1); leave B(1) in flight
  stgA(0,0,0); stgA(0,1,0); stgB(0,0,0); stgB(0,1,0); stgB(1,0,1); stgB(1,1,1);
  asm volatile("s_waitcnt vmcnt(4)" ::: "memory");
  BARRAW;

#define PHASE(BUF, Q, STAGE, VM)                                           \
  {                                                                        \
    unsigned a0 = apAb + (BUF)*32768u + (Q)*4096u + ua0b;                  \
    unsigned a1 = apAb + (BUF)*32768u + (Q)*4096u + ua1b;                  \
    bf16x8 a00 = dsr<0>(a0);                                               \
    bf16x8 a10 = dsr<2048>(a0);                                            \
    bf16x8 a01 = dsr<0>(a1);                                               \
    bf16x8 a11 = dsr<2048>(a1);                                            \
    if((Q) == 0){                                                          \
      unsigned b0 = apBb + (BUF)*32768u + ua0b;                            \
      unsigned b1 = apBb + (BUF)*32768u + ua1b;                            \
      bfr[0][0] = dsr<0>(b0);    bfr[1][0] = dsr<2048>(b0);                \
      bfr[2][0] = dsr<4096>(b0); bfr[3][0] = dsr<6144>(b0);                \
      bfr[0][1] = dsr<0>(b1);    bfr[1][1] = dsr<2048>(b1);                \
      bfr[2][1] = dsr<4096>(b1); bfr[3][1] = dsr<6144>(b1);                \
    }                                                                      \
    STAGE;                                                                 \
    BARRAW;                                                                \
    asm volatile("s_waitcnt lgkmcnt(0)" ::: "memory");                     \
    __builtin_amdgcn_sched_barrier(0);                                     \
    __builtin_amdgcn_s_setprio(1);                                         \
    _Pragma("unroll")                                                      \
    for(int ni=0;ni<4;ni++){                                               \
      acc[2*(Q)][ni]   = MFMA16(a00, bfr[ni][0], acc[2*(Q)][ni]);          \
      acc[2*(Q)+1][ni] = MFMA16(a10, bfr[ni][0], acc[2*(Q)+1][ni]);        \
    }                                                                      \
    _Pragma("unroll")                                                      \
    for(int ni=0;ni<4;ni++){                                               \
      acc[2*(Q)][ni]   = MFMA16(a01, bfr[ni][1], acc[2*(Q)][ni]);          \
      acc[2*(Q)+1][ni] = MFMA16(a11, bfr[ni][1], acc[2*(Q)+1][ni]);        \
    }                                                                      \
    __builtin_amdgcn_s_setprio(0);                                         \
    VM;                                                                    \
    BARRAW;                                                                \
  }

#define VMW asm volatile("s_waitcnt vmcnt(4)" ::: "memory")

#pragma unroll 1
  for(int i=0;i<16;i++){
    int t1 = 2*i+1, t2 = (2*i+2)&31, t3 = (2*i+3)&31;
    PHASE(0, 0, stgA(1,0,t1), );
    PHASE(0, 1, stgA(1,1,t1), );
    PHASE(0, 2, stgB(0,0,t2), );
    PHASE(0, 3, stgB(0,1,t2), VMW);
    PHASE(1, 0, stgA(0,0,t2), );
    PHASE(1, 1, stgA(0,1,t2), );
    PHASE(1, 2, stgB(1,0,t3), );
    PHASE(1, 3, stgB(1,1,t3), VMW);
  }
#undef PHASE
#undef VMW
  asm volatile("s_waitcnt vmcnt(0)" ::: "memory");

  // epilogue: QKV scatter
#pragma unroll
  for(int mi=0;mi<8;mi++){
#pragma unroll
    for(int ni=0;ni<4;ni++){
      int n = n0 + wn*64 + ni*16 + lr;
      int seg = n >> 11;
      int h = (n >> 7) & 15, d = n & 127;
#pragma unroll
      for(int r=0;r<4;r++){
        int mrow = m0 + wm*128 + mi*16 + lg*4 + r;
        float v = acc[mi][ni][r];
        int b = mrow >> 10, t = mrow & 1023;
        if(seg == 0){
          q_ws[((size_t)(b*Hh + h)*Tt + t)*Dd + d] = f2bf(v * QSCALE);
        } else if(seg == 1){
          int key = TC + t;
          size_t base = (size_t)(b*Hh + h)*CTX + key;
          out_k[base*Dd + d] = v;
          int dp = (((d>>3) ^ (key&7)) << 3) | (d & 7);
          Kws[base*Dd + dp] = f2bf(v);
        } else {
          out_v[((size_t)(b*Hh + h)*CTX + TC + t)*Dd + d] = v;
        }
      }
    }
  }
}

// ---- 128x128 BK=32 GEMM (proj): A, BT bf16 MODE-0 swizzled, stride LDP ----
__global__ __launch_bounds__(256) void gemmp_k(
    const unsigned short* __restrict__ A, const unsigned short* __restrict__ BT,
    const float* __restrict__ bias, float* __restrict__ outp){
  constexpr int K = 2048;
  __shared__ unsigned short Al[2][128*32];
  __shared__ unsigned short Bl[2][128*32];
  int tid = threadIdx.x, lane = tid & 63, w = tid >> 6;
  int lr = lane & 15, lg = lane >> 4;
  int m0 = blockIdx.x * 128, n0 = blockIdx.y * 128;
  int wr = (w >> 1) * 64, wc = (w & 1) * 64;
  int swz = (lg ^ ((lr >> 1) & 3)) << 3;

  unsigned baseAb = ldsoff(Al) + (unsigned)(((wr + lr)*32 + swz)*2);
  unsigned baseBb = ldsoff(Bl) + (unsigned)(((wc + lr)*32 + swz)*2);

  f32x4 acc[4][4];
#pragma unroll
  for(int i=0;i<4;i++)
#pragma unroll
    for(int j=0;j<4;j++) acc[i][j] = (f32x4){0.f,0.f,0.f,0.f};

  auto stage = [&](int buf, int k0){
#pragma unroll
    for(int li=0; li<2; li++){
      int rb = w*32 + li*16;
      gld16(A  + (size_t)(m0 + rb + (lane>>2))*LDP + k0 + (lane&3)*8, &Al[buf][rb*32]);
      gld16(BT + (size_t)(n0 + rb + (lane>>2))*LDP + k0 + (lane&3)*8, &Bl[buf][rb*32]);
    }
  };
  stage(0, 0);
  __syncthreads();
  int buf = 0;
  for(int k0 = 0; k0 < K; k0 += 32){
    if(k0 + 32 < K) stage(buf^1, k0 + 32);
    unsigned aA = baseAb + (unsigned)buf*8192u;
    unsigned aB = baseBb + (unsigned)buf*8192u;
    bf16x8 af[4], bfr[4];
    af[0]  = dsr<0>(aA);    af[1]  = dsr<1024>(aA);
    af[2]  = dsr<2048>(aA); af[3]  = dsr<3072>(aA);
    bfr[0] = dsr<0>(aB);    bfr[1] = dsr<1024>(aB);
    bfr[2] = dsr<2048>(aB); bfr[3] = dsr<3072>(aB);
    asm volatile("s_waitcnt lgkmcnt(0)" ::: "memory");
    __builtin_amdgcn_sched_barrier(0);
#pragma unroll
    for(int mi=0;mi<4;mi++)
#pragma unroll
      for(int ni=0;ni<4;ni++)
        acc[mi][ni] = MFMA16(af[mi], bfr[ni], acc[mi][ni]);
    __syncthreads();
    buf ^= 1;
  }

#pragma unroll
  for(int mi=0;mi<4;mi++){
#pragma unroll
    for(int ni=0;ni<4;ni++){
      int n = n0 + wc + ni*16 + lr;
#pragma unroll
      for(int r=0;r<4;r++){
        int mrow = m0 + wr + mi*16 + lg*4 + r;
        outp[(size_t)mrow * Cc + n] = acc[mi][ni][r] + bias[n];
      }
    }
  }
}

// ---- flash attention, swapped-QK 32x32, 4 waves x 32q, key-split x2 ----
__global__ __launch_bounds__(256, 2) void attn_k(
    const unsigned short* __restrict__ q_ws,
    const unsigned short* __restrict__ Kws,
    const unsigned short* __restrict__ Vt,
    float* __restrict__ O0, unsigned short* __restrict__ O1b,
    float* __restrict__ ml){
  __shared__ unsigned short Kl[2][64*128];   // [key][128] swizzled
  __shared__ unsigned short Vl[2][128*64];   // [d][64]  swizzled
  int tid = threadIdx.x, lane = tid & 63, w = tid >> 6;
  int l31 = lane & 31, hi = lane >> 5, r7 = l31 & 7;
  int qt = blockIdx.x, split = blockIdx.y, bh = blockIdx.z;
  int q0b = qt * 128, qw0 = q0b + w * 32;
  const unsigned short* Kb = Kws + (size_t)bh * CTX * Dd;
  const unsigned short* Vb = Vt  + (size_t)bh * Dd * VS;

  const unsigned short* qp = q_ws + ((size_t)bh * Tt + qw0 + l31) * Dd + hi * 8;
  bf16x8 qf[8];
#pragma unroll
  for(int ks=0;ks<8;ks++) qf[ks] = *(const bf16x8*)(qp + ks*16);

  f32x16 o[4];
#pragma unroll
  for(int dt=0;dt<4;dt++)
#pragma unroll
    for(int r=0;r<16;r++) o[dt][r] = 0.f;
  float m = -3e38f, l = 0.f;

  int nts = ((TC + q0b + 128) >> 6) >> 1;   // tiles for this split

  auto stageK = [&](int buf, int j0){
#pragma unroll
    for(int li=0; li<4; li++){
      gld16(Kb + (size_t)(j0 + w*16 + li*4 + (lane>>4))*Dd + (lane&15)*8,
            &Kl[buf][(w*16 + li*4)*128]);
    }
  };
  auto stageV = [&](int buf, int j0){
#pragma unroll
    for(int li=0; li<4; li++){
      gld16(Vb + (size_t)(w*32 + li*8 + (lane>>3))*VS + j0 + (lane&7)*8,
            &Vl[buf][(w*32 + li*8)*64]);
    }
  };

  stageK(0, split*64); stageV(0, split*64);
  __syncthreads();
  int buf = 0;
#pragma unroll 1
  for(int t = 0; t < nts; t++){
    int j0 = (2*t + split) * 64;
    if(t + 1 < nts){ stageK(buf^1, j0 + 128); stageV(buf^1, j0 + 128); }

    if(j0 <= TC + qw0 + 31){
      f32x16 s0, s1;
#pragma unroll
      for(int r=0;r<16;r++){ s0[r] = 0.f; s1[r] = 0.f; }
#pragma unroll
      for(int ks=0; ks<8; ks++){
        int ub = ((ks*2 + hi) ^ r7) << 3;
        bf16x8 kf0 = *(const bf16x8*)&Kl[buf][l31*128 + ub];
        bf16x8 kf1 = *(const bf16x8*)&Kl[buf][(32+l31)*128 + ub];
        s0 = mfma32(kf0, qf[ks], s0);
        s1 = mfma32(kf1, qf[ks], s1);
      }
      int qabs = TC + qw0 + l31;
      if(j0 + 63 > TC + qw0){
#pragma unroll
        for(int r=0;r<16;r++){
          int kk = (r&3) + 8*(r>>2) + 4*hi;
          if(j0 + kk > qabs)      s0[r] = -1e30f;
          if(j0 + 32 + kk > qabs) s1[r] = -1e30f;
        }
      }
      float tm = fmaxf(s0[0], s1[0]);
#pragma unroll
      for(int r=1;r<16;r++) tm = fmaxf(tm, fmaxf(s0[r], s1[r]));
      tm = fmaxf(tm, __shfl_xor(tm, 32, 64));
      if(!__all(tm - m <= 8.f)){
        float mn = fmaxf(m, tm);
        float alpha = __expf(m - mn);
        m = mn;
        l *= alpha;
        float ar[16];
#pragma unroll
        for(int r=0;r<16;r++){
          int kk = (r&3) + 8*(r>>2) + 4*hi;
          ar[r] = __shfl(alpha, kk, 64);
        }
#pragma unroll
        for(int dt=0;dt<4;dt++)
#pragma unroll
          for(int r=0;r<16;r++) o[dt][r] *= ar[r];
      }
#pragma unroll
      for(int r=0;r<16;r++){ s0[r] = __expf(s0[r] - m); s1[r] = __expf(s1[r] - m); }
      float ts = 0.f;
#pragma unroll
      for(int r=0;r<16;r++) ts += s0[r] + s1[r];
      ts += __shfl_xor(ts, 32, 64);
      l += ts;
#pragma unroll
      for(int ks16=0; ks16<4; ks16++){
        f32x16 p = (ks16 & 2) ? s1 : s0;
        int fb = (ks16 & 1) * 8;
        unsigned e0 = pk2(p[fb+0], p[fb+1]);
        unsigned e1 = pk2(p[fb+2], p[fb+3]);
        unsigned e2 = pk2(p[fb+4], p[fb+5]);
        unsigned e3 = pk2(p[fb+6], p[fb+7]);
        unsigned x0 = __shfl_xor(e0, 32, 64);
        unsigned x1 = __shfl_xor(e1, 32, 64);
        unsigned x2 = __shfl_xor(e2, 32, 64);
        unsigned x3 = __shfl_xor(e3, 32, 64);
        bf16x8 pa = mk4(hi ? x2 : e0, hi ? x3 : e1, hi ? e2 : x0, hi ? e3 : x1);
        int ub = ((ks16*2 + hi) ^ r7) << 3;
#pragma unroll
        for(int dt=0; dt<4; dt++){
          bf16x8 vf = *(const bf16x8*)&Vl[buf][(dt*32 + l31)*64 + ub];
          o[dt] = mfma32(pa, vf, o[dt]);
        }
      }
    }
    __syncthreads();
    buf ^= 1;
  }

  if(split == 0){
#pragma unroll
    for(int dt=0; dt<4; dt++)
#pragma unroll
      for(int r=0; r<16; r++){
        int q = qw0 + (r&3) + 8*(r>>2) + 4*hi;
        O0[((size_t)bh*Tt + q)*Dd + dt*32 + l31] = o[dt][r];
      }
  } else {
#pragma unroll
    for(int dt=0; dt<4; dt++)
#pragma unroll
      for(int r=0; r<16; r++){
        int q = qw0 + (r&3) + 8*(r>>2) + 4*hi;
        O1b[((size_t)bh*Tt + q)*Dd + dt*32 + l31] = f2bf(o[dt][r]);
      }
  }
  if(lane < 32){
    float* mlp = ml + (((size_t)split*32 + bh)*Tt + qw0 + l31)*2;
    mlp[0] = m; mlp[1] = l;
  }
}

// ---- combine split partials -> bf16 attn_ws (MODE-0 swizzle, stride LDP) ----
__global__ __launch_bounds__(256) void combine_k(
    const float* __restrict__ O0, const unsigned short* __restrict__ O1b,
    const float* __restrict__ ml, unsigned short* __restrict__ attn_ws){
  int tid = threadIdx.x;
  int d = tid & 127, rl = tid >> 7;
  int row = blockIdx.x * 2 + rl;          // bh*1024 + t
  int bh = row >> 10, t = row & 1023;
  const float* p0 = ml + ((size_t)bh * Tt + t) * 2;
  const float* p1 = ml + (((size_t)32 + bh) * Tt + t) * 2;
  float m0 = p0[0], l0 = p0[1], m1 = p1[0], l1 = p1[1];
  float M = fmaxf(m0, m1);
  float e0 = __expf(m0 - M), e1 = __expf(m1 - M);
  float inv = 1.f / (l0*e0 + l1*e1);
  size_t off = (size_t)row * Dd + d;
  float v = (O0[off]*e0 + bf2f(O1b[off])*e1) * inv;
  int b = bh >> 4, h = bh & 15;
  int mrow = b * Tt + t;
  int c = h * Dd + d;
  int cp = (c & ~24) | ((((c>>3)&3) ^ ((mrow>>1)&3)) << 3);
  attn_ws[(size_t)mrow * LDP + cp] = f2bf(v);
}

extern "C" void kernel_launch(void* const* d_in, const int* in_sizes, int n_in,
                              void* d_out, int out_size, void* d_ws, size_t ws_size,
                              hipStream_t stream){
  const float* x       = (const float*)d_in[0];
  const float* cache_k = (const float*)d_in[1];
  const float* cache_v = (const float*)d_in[2];
  const float* W_qkv   = (const float*)d_in[3];
  const float* W_proj  = (const float*)d_in[4];
  const float* b_proj  = (const float*)d_in[5];

  float* out   = (float*)d_out;
  float* out_k = out   + (size_t)Bb*Tt*Cc;
  float* out_v = out_k + (size_t)Bb*Hh*CTX*Dd;

  if(ws_size < (size_t)67108864) return;  // need 64 MiB scratch
  char* ws = (char*)d_ws;
  // liveness-packed layout (timeline: pre, gemm8, mid, attn, combine, gemmp)
  unsigned short* WqkvT  = (unsigned short*)(ws);              // [0,25952256) 6144x2112
  unsigned short* Vt_ws  = (unsigned short*)(ws);              // [0,17039360) after gemm8
  unsigned short* attn_ws= (unsigned short*)(ws);              // [0,8650752) after attn
  unsigned short* WprojT = (unsigned short*)(ws + 17039360);   // [17039360,25690112)
  unsigned short* Kws    = (unsigned short*)(ws + 25952256);   // [25952256,42729472)
  unsigned short* q_ws   = (unsigned short*)(ws + 42729472);   // [42729472,51118080)
  unsigned short* x_bf   = (unsigned short*)(ws + 51118080);   // [51118080,59768832)
  unsigned short* O1b    = (unsigned short*)(ws + 51118080);   // after gemm8 (attn out)
  float*          ml     = (float*)(ws + 59768832);            // [59768832,60293120)
  float*          O0     = out;                                // out slot as scratch

  fused_pre_k<<<dim3(20480), 256, 0, stream>>>(
      W_qkv, WqkvT, (const float4*)x, x_bf,
      (const float4*)cache_k, (const float4*)cache_v,
      (float4*)out_k, (float4*)out_v, Kws);
  gemm8_k<<<dim3(192), 512, 0, stream>>>(x_bf, WqkvT, q_ws, out_k, out_v, Kws);
  fused_mid_k<<<dim3(12288), 256, 0, stream>>>(out_v, Vt_ws, W_proj, WprojT);
  attn_k<<<dim3(8,2,32), 256, 0, stream>>>(q_ws, Kws, Vt_ws, O0, O1b, ml);
  combine_k<<<dim3(16384), 256, 0, stream>>>(O0, O1b, ml, attn_ws);
  gemmp_k<<<dim3(16,16), 256, 0, stream>>>(attn_ws, WprojT, b_proj, out);
}

// Round 7
// 200.373 us; speedup vs baseline: 1.5531x; 1.0415x over previous
//
#include <hip/hip_runtime.h>
#include <hip/hip_bf16.h>

typedef __attribute__((ext_vector_type(8))) short bf16x8;
typedef __attribute__((ext_vector_type(4))) float f32x4;
typedef __attribute__((ext_vector_type(16))) float f32x16;

#define DI __device__ __forceinline__

static constexpr int Bb  = 2;
static constexpr int Tt  = 1024;
static constexpr int Cc  = 2048;
static constexpr int Hh  = 16;
static constexpr int Dd  = 128;
static constexpr int TC  = 1024;   // cached tokens (seq_start)
static constexpr int CTX = 2048;   // total context
static constexpr int LDP = 2112;   // padded row stride for GEMM operands
static constexpr int VS  = 2080;   // padded Vt row stride
static constexpr float QSCALE = 0.08838834764831845f; // 1/sqrt(128)

DI unsigned short f2bf(float f){
  unsigned u = __builtin_bit_cast(unsigned, f);
  u += 0x7FFFu + ((u >> 16) & 1u);
  return (unsigned short)(u >> 16);
}
DI float bf2f(unsigned short s){
  return __builtin_bit_cast(float, (unsigned)s << 16);
}
DI unsigned pk2(float a, float b){
  return (unsigned)f2bf(a) | ((unsigned)f2bf(b) << 16);
}
DI bf16x8 mk4(unsigned a, unsigned b, unsigned c, unsigned d){
  union{ unsigned u[4]; bf16x8 v; } x;
  x.u[0]=a; x.u[1]=b; x.u[2]=c; x.u[3]=d; return x.v;
}
DI f32x16 mfma32(bf16x8 a, bf16x8 b, f32x16 c){
  return __builtin_amdgcn_mfma_f32_32x32x16_bf16(a, b, c, 0, 0, 0);
}
#define MFMA16(a,b,c) __builtin_amdgcn_mfma_f32_16x16x32_bf16(a,b,c,0,0,0)
DI void gld16(const void* g, void* l){
  __builtin_amdgcn_global_load_lds(
      (const __attribute__((address_space(1))) unsigned int*)g,
      (__attribute__((address_space(3))) unsigned int*)l, 16, 0, 0);
}
DI unsigned ldsoff(const void* p){
  return (unsigned)(size_t)(const __attribute__((address_space(3))) void*)p;
}
// inline-asm LDS read: compiler-invisible (manual lgkmcnt + sched_barrier required)
template<int OFF>
DI bf16x8 dsr(unsigned addr){
  bf16x8 v;
  if constexpr (OFF == 0)
    asm volatile("ds_read_b128 %0, %1" : "=v"(v) : "v"(addr));
  else
    asm volatile("ds_read_b128 %0, %1 offset:%2" : "=v"(v) : "v"(addr), "i"(OFF));
  return v;
}
// NO-CLOBBER fences: invisible to the waitcnt pass (no mayLoad/mayStore),
// so no implicit vmcnt(0) drain of in-flight LDS-DMA is inserted around them.
#define BARNC   asm volatile("s_barrier")
#define LGKM0   asm volatile("s_waitcnt lgkmcnt(0)")
#define VMCNT4  asm volatile("s_waitcnt vmcnt(4)")
#define VMCNT0  asm volatile("s_waitcnt vmcnt(0)")
#define SBAR    __builtin_amdgcn_sched_barrier(0)

// ---- shared transpose body: fp32 [R][C] -> bf16 [C][ostride] swizzled ----
DI void transpose_body(const float* in, unsigned short* out,
                       int R, int C, int ostride, int r0, int c0, int mode,
                       unsigned short (*tile)[33]){
  int tx = threadIdx.x & 31, ty = threadIdx.x >> 5;
#pragma unroll
  for(int i=0;i<4;i++){
    int r = r0 + ty + i*8;
    tile[ty + i*8][tx] = f2bf(in[(size_t)r * C + c0 + tx]);
  }
  __syncthreads();
#pragma unroll
  for(int i=0;i<4;i++){
    int c = c0 + ty + i*8;     // out row
    int k = r0 + tx;           // out col (logical)
    int kp;
    if(mode == 0)
      kp = (k & ~24) | ((((k>>3)&3) ^ ((c>>1)&3)) << 3);
    else
      kp = (k & ~56) | ((((k>>3)&7) ^ (c&7)) << 3);
    out[(size_t)c * ostride + kp] = tile[tx][ty + i*8];
  }
}

// ---- fused pre-work: W_qkv transpose + x conv + cache copy ----
__global__ __launch_bounds__(256) void fused_pre_k(
    const float* __restrict__ W_qkv, unsigned short* __restrict__ WqkvT,
    const float4* __restrict__ x4, unsigned short* __restrict__ xbf,
    const float4* __restrict__ ck, const float4* __restrict__ cv,
    float4* __restrict__ ok, float4* __restrict__ ov,
    unsigned short* __restrict__ Kws){
  __shared__ unsigned short tile[32][33];
  int bid = blockIdx.x;
  if(bid < 12288){
    int bx = bid % 192, by = bid / 192;
    transpose_body(W_qkv, WqkvT, 2048, 6144, LDP, by*32, bx*32, 1, tile);
  } else if(bid < 16384){
    int idx = (bid - 12288) * 256 + threadIdx.x;   // x: 2048*2048/4
    int m = idx >> 9;
    int c4 = (idx & 511) * 4;
    float4 v = x4[idx];
    int cp = ((((c4>>3) ^ (m&7)) << 3)) | (c4 & 7);
    uint2 p; p.x = pk2(v.x, v.y); p.y = pk2(v.z, v.w);
    *(uint2*)(xbf + (size_t)m * LDP + cp) = p;
  } else {
    int idx = (bid - 16384) * 256 + threadIdx.x;
    const int per = TC * Dd / 4;                 // 32768 per (b,h)
    int bh = idx / per, r = idx - bh * per;
    int dst = bh * (CTX * Dd / 4) + r;
    float4 kv = ck[idx];
    ok[dst] = kv;
    ov[dst] = cv[idx];
    int key = r >> 5, dq = (r & 31) * 4;
    int dp = (((dq>>3) ^ (key&7)) << 3) | (dq & 7);
    uint2 p; p.x = pk2(kv.x, kv.y); p.y = pk2(kv.z, kv.w);
    *(uint2*)(Kws + ((size_t)bh * CTX + key) * Dd + dp) = p;
  }
}

// ---- fused mid-work: V^T (per bh) + W_proj^T ----
__global__ __launch_bounds__(256) void fused_mid_k(
    const float* __restrict__ out_v, unsigned short* __restrict__ Vt_ws,
    const float* __restrict__ W_proj, unsigned short* __restrict__ WprojT){
  __shared__ unsigned short tile[32][33];
  int bid = blockIdx.x;
  if(bid < 8192){
    int z = bid >> 8, rem = bid & 255;
    int bx = rem & 3, by = rem >> 2;
    transpose_body(out_v + (size_t)z*2048*128, Vt_ws + (size_t)z*128*VS,
                   2048, 128, VS, by*32, bx*32, 1, tile);
  } else {
    int b2 = bid - 8192;
    int bx = b2 & 63, by = b2 >> 6;
    transpose_body(W_proj, WprojT, 2048, 2048, LDP, by*32, bx*32, 0, tile);
  }
}

// ================= 256x256 8-phase GEMM (QKV) =================
__global__ __launch_bounds__(512) void gemm8_k(
    const unsigned short* __restrict__ A, const unsigned short* __restrict__ BT,
    unsigned short* __restrict__ q_ws, float* __restrict__ out_k,
    float* __restrict__ out_v, unsigned short* __restrict__ Kws){
  __shared__ unsigned short lds[65536];        // A: [0,32768) B: [32768,65536) elems
  int tid = threadIdx.x, lane = tid & 63, w = tid >> 6;
  int lr = lane & 15, lg = lane >> 4;
  int wm = w >> 2, wn = w & 3;
  int bid = blockIdx.x;                        // 192 blocks, 192%8==0
  int swz = (bid & 7) * 24 + (bid >> 3);       // bijective XCD swizzle
  int m0 = (swz & 7) * 256;
  int n0 = (swz >> 3) * 256;

  int r8 = lane >> 3, c8 = (lane & 7) * 8;
  const unsigned short* Asrc = A  + (size_t)(m0 + w*16 + r8)*LDP + c8;
  const unsigned short* Bsrc = BT + (size_t)(n0 + w*16 + r8)*LDP + c8;
  unsigned short* ldsA = lds;
  unsigned short* ldsB = lds + 32768;

  auto stgA = [&](int b, int h, int kt){
    const unsigned short* s = Asrc + (size_t)(h*128)*LDP + kt*64;
    unsigned short* d = ldsA + b*16384 + h*8192 + w*1024;
    gld16(s, d);
    gld16(s + (size_t)8*LDP, d + 512);
  };
  auto stgB = [&](int b, int h, int kt){
    const unsigned short* s = Bsrc + (size_t)(h*128)*LDP + kt*64;
    unsigned short* d = ldsB + b*16384 + h*8192 + w*1024;
    gld16(s, d);
    gld16(s + (size_t)8*LDP, d + 512);
  };

  // byte addresses for asm ds_read
  unsigned LB   = ldsoff(lds);
  unsigned apAb = LB + (unsigned)(wm*128 + lr)*128;            // A row base (bytes)
  unsigned apBb = LB + 65536u + (unsigned)(wn*64 + lr)*128;    // B row base (bytes)
  unsigned ua0b = (unsigned)(( lg      ^ (lr & 7)) * 16);      // kk=0 unit (bytes)
  unsigned ua1b = (unsigned)(((4 + lg) ^ (lr & 7)) * 16);      // kk=1 unit (bytes)

  f32x4 acc[8][4];
#pragma unroll
  for(int i=0;i<8;i++)
#pragma unroll
    for(int j=0;j<4;j++) acc[i][j] = (f32x4){0.f,0.f,0.f,0.f};
  bf16x8 bfr[4][2];

  // prologue: K-tile0 fully + B(1); leave B(1) in flight
  stgA(0,0,0); stgA(0,1,0); stgB(0,0,0); stgB(0,1,0); stgB(1,0,1); stgB(1,1,1);
  SBAR;
  VMCNT4;
  BARNC;

#define PHASE(BUF, Q, STAGE, VM)                                           \
  {                                                                        \
    unsigned a0 = apAb + (BUF)*32768u + (Q)*4096u + ua0b;                  \
    unsigned a1 = apAb + (BUF)*32768u + (Q)*4096u + ua1b;                  \
    bf16x8 a00 = dsr<0>(a0);                                               \
    bf16x8 a10 = dsr<2048>(a0);                                            \
    bf16x8 a01 = dsr<0>(a1);                                               \
    bf16x8 a11 = dsr<2048>(a1);                                            \
    if((Q) == 0){                                                          \
      unsigned b0 = apBb + (BUF)*32768u + ua0b;                            \
      unsigned b1 = apBb + (BUF)*32768u + ua1b;                            \
      bfr[0][0] = dsr<0>(b0);    bfr[1][0] = dsr<2048>(b0);                \
      bfr[2][0] = dsr<4096>(b0); bfr[3][0] = dsr<6144>(b0);                \
      bfr[0][1] = dsr<0>(b1);    bfr[1][1] = dsr<2048>(b1);                \
      bfr[2][1] = dsr<4096>(b1); bfr[3][1] = dsr<6144>(b1);                \
    }                                                                      \
    SBAR;                                                                  \
    STAGE;                                                                 \
    SBAR;                                                                  \
    BARNC;                                                                 \
    LGKM0;                                                                 \
    SBAR;                                                                  \
    __builtin_amdgcn_s_setprio(1);                                         \
    _Pragma("unroll")                                                      \
    for(int ni=0;ni<4;ni++){                                               \
      acc[2*(Q)][ni]   = MFMA16(a00, bfr[ni][0], acc[2*(Q)][ni]);          \
      acc[2*(Q)+1][ni] = MFMA16(a10, bfr[ni][0], acc[2*(Q)+1][ni]);        \
    }                                                                      \
    _Pragma("unroll")                                                      \
    for(int ni=0;ni<4;ni++){                                               \
      acc[2*(Q)][ni]   = MFMA16(a01, bfr[ni][1], acc[2*(Q)][ni]);          \
      acc[2*(Q)+1][ni] = MFMA16(a11, bfr[ni][1], acc[2*(Q)+1][ni]);        \
    }                                                                      \
    __builtin_amdgcn_s_setprio(0);                                         \
    SBAR;                                                                  \
    VM;                                                                    \
    BARNC;                                                                 \
  }

#pragma unroll 1
  for(int i=0;i<16;i++){
    int t1 = 2*i+1, t2 = (2*i+2)&31, t3 = (2*i+3)&31;
    PHASE(0, 0, stgA(1,0,t1), );
    PHASE(0, 1, stgA(1,1,t1), );
    PHASE(0, 2, stgB(0,0,t2), );
    PHASE(0, 3, stgB(0,1,t2), VMCNT4);
    PHASE(1, 0, stgA(0,0,t2), );
    PHASE(1, 1, stgA(0,1,t2), );
    PHASE(1, 2, stgB(1,0,t3), );
    PHASE(1, 3, stgB(1,1,t3), VMCNT4);
  }
#undef PHASE
  asm volatile("s_waitcnt vmcnt(0)" ::: "memory");

  // epilogue: QKV scatter
#pragma unroll
  for(int mi=0;mi<8;mi++){
#pragma unroll
    for(int ni=0;ni<4;ni++){
      int n = n0 + wn*64 + ni*16 + lr;
      int seg = n >> 11;
      int h = (n >> 7) & 15, d = n & 127;
#pragma unroll
      for(int r=0;r<4;r++){
        int mrow = m0 + wm*128 + mi*16 + lg*4 + r;
        float v = acc[mi][ni][r];
        int b = mrow >> 10, t = mrow & 1023;
        if(seg == 0){
          q_ws[((size_t)(b*Hh + h)*Tt + t)*Dd + d] = f2bf(v * QSCALE);
        } else if(seg == 1){
          int key = TC + t;
          size_t base = (size_t)(b*Hh + h)*CTX + key;
          out_k[base*Dd + d] = v;
          int dp = (((d>>3) ^ (key&7)) << 3) | (d & 7);
          Kws[base*Dd + dp] = f2bf(v);
        } else {
          out_v[((size_t)(b*Hh + h)*CTX + TC + t)*Dd + d] = v;
        }
      }
    }
  }
}

// ---- 128x128 BK=32 GEMM (proj): counted-vmcnt + no-clobber fences ----
__global__ __launch_bounds__(256) void gemmp_k(
    const unsigned short* __restrict__ A, const unsigned short* __restrict__ BT,
    const float* __restrict__ bias, float* __restrict__ outp){
  constexpr int K = 2048;
  __shared__ unsigned short Al[2][128*32];
  __shared__ unsigned short Bl[2][128*32];
  int tid = threadIdx.x, lane = tid & 63, w = tid >> 6;
  int lr = lane & 15, lg = lane >> 4;
  int m0 = blockIdx.x * 128, n0 = blockIdx.y * 128;
  int wr = (w >> 1) * 64, wc = (w & 1) * 64;
  int swz = (lg ^ ((lr >> 1) & 3)) << 3;

  unsigned baseAb = ldsoff(Al) + (unsigned)(((wr + lr)*32 + swz)*2);
  unsigned baseBb = ldsoff(Bl) + (unsigned)(((wc + lr)*32 + swz)*2);

  f32x4 acc[4][4];
#pragma unroll
  for(int i=0;i<4;i++)
#pragma unroll
    for(int j=0;j<4;j++) acc[i][j] = (f32x4){0.f,0.f,0.f,0.f};

  auto stage = [&](int buf, int k0){
#pragma unroll
    for(int li=0; li<2; li++){
      int rb = w*32 + li*16;
      gld16(A  + (size_t)(m0 + rb + (lane>>2))*LDP + k0 + (lane&3)*8, &Al[buf][rb*32]);
      gld16(BT + (size_t)(n0 + rb + (lane>>2))*LDP + k0 + (lane&3)*8, &Bl[buf][rb*32]);
    }
  };
  stage(0, 0);                      // 4 loads in flight
  int buf = 0;
#pragma unroll 1
  for(int k0 = 0; k0 < K; k0 += 32){
    SBAR;
    if(k0 + 32 < K){
      stage(buf^1, k0 + 32);        // +4 -> 8 in flight
      SBAR;
      VMCNT4;                       // wait: buf's 4 landed; next-buf 4 stay in flight
    } else {
      SBAR;
      VMCNT0;
    }
    BARNC;                          // all waves' buf loads landed
    unsigned aA = baseAb + (unsigned)buf*8192u;
    unsigned aB = baseBb + (unsigned)buf*8192u;
    bf16x8 af[4], bfr[4];
    af[0]  = dsr<0>(aA);    af[1]  = dsr<1024>(aA);
    af[2]  = dsr<2048>(aA); af[3]  = dsr<3072>(aA);
    bfr[0] = dsr<0>(aB);    bfr[1] = dsr<1024>(aB);
    bfr[2] = dsr<2048>(aB); bfr[3] = dsr<3072>(aB);
    LGKM0;
    SBAR;
    __builtin_amdgcn_s_setprio(1);
#pragma unroll
    for(int mi=0;mi<4;mi++)
#pragma unroll
      for(int ni=0;ni<4;ni++)
        acc[mi][ni] = MFMA16(af[mi], bfr[ni], acc[mi][ni]);
    __builtin_amdgcn_s_setprio(0);
    SBAR;
    BARNC;                          // reads done before next stage overwrites buf^1... wait: next stage writes buf^1 (old buf after flip)
    buf ^= 1;
  }

#pragma unroll
  for(int mi=0;mi<4;mi++){
#pragma unroll
    for(int ni=0;ni<4;ni++){
      int n = n0 + wc + ni*16 + lr;
#pragma unroll
      for(int r=0;r<4;r++){
        int mrow = m0 + wr + mi*16 + lg*4 + r;
        outp[(size_t)mrow * Cc + n] = acc[mi][ni][r] + bias[n];
      }
    }
  }
}

// ---- flash attention, swapped-QK 32x32, 4 waves x 32q, key-split x2 ----
__global__ __launch_bounds__(256, 2) void attn_k(
    const unsigned short* __restrict__ q_ws,
    const unsigned short* __restrict__ Kws,
    const unsigned short* __restrict__ Vt,
    float* __restrict__ O0, unsigned short* __restrict__ O1b,
    float* __restrict__ ml){
  __shared__ unsigned short Kl[2][64*128];   // [key][128] swizzled
  __shared__ unsigned short Vl[2][128*64];   // [d][64]  swizzled
  int tid = threadIdx.x, lane = tid & 63, w = tid >> 6;
  int l31 = lane & 31, hi = lane >> 5, r7 = l31 & 7;
  int qt = blockIdx.x, split = blockIdx.y, bh = blockIdx.z;
  int q0b = qt * 128, qw0 = q0b + w * 32;
  const unsigned short* Kb = Kws + (size_t)bh * CTX * Dd;
  const unsigned short* Vb = Vt  + (size_t)bh * Dd * VS;

  const unsigned short* qp = q_ws + ((size_t)bh * Tt + qw0 + l31) * Dd + hi * 8;
  bf16x8 qf[8];
#pragma unroll
  for(int ks=0;ks<8;ks++) qf[ks] = *(const bf16x8*)(qp + ks*16);

  f32x16 o[4];
#pragma unroll
  for(int dt=0;dt<4;dt++)
#pragma unroll
    for(int r=0;r<16;r++) o[dt][r] = 0.f;
  float m = -3e38f, l = 0.f;

  int nts = ((TC + q0b + 128) >> 6) >> 1;   // tiles for this split

  auto stageK = [&](int buf, int j0){
#pragma unroll
    for(int li=0; li<4; li++){
      gld16(Kb + (size_t)(j0 + w*16 + li*4 + (lane>>4))*Dd + (lane&15)*8,
            &Kl[buf][(w*16 + li*4)*128]);
    }
  };
  auto stageV = [&](int buf, int j0){
#pragma unroll
    for(int li=0; li<4; li++){
      gld16(Vb + (size_t)(w*32 + li*8 + (lane>>3))*VS + j0 + (lane&7)*8,
            &Vl[buf][(w*32 + li*8)*64]);
    }
  };

  stageK(0, split*64); stageV(0, split*64);
  __syncthreads();
  int buf = 0;
#pragma unroll 1
  for(int t = 0; t < nts; t++){
    int j0 = (2*t + split) * 64;
    if(t + 1 < nts){ stageK(buf^1, j0 + 128); stageV(buf^1, j0 + 128); }

    if(j0 <= TC + qw0 + 31){
      f32x16 s0, s1;
#pragma unroll
      for(int r=0;r<16;r++){ s0[r] = 0.f; s1[r] = 0.f; }
#pragma unroll
      for(int ks=0; ks<8; ks++){
        int ub = ((ks*2 + hi) ^ r7) << 3;
        bf16x8 kf0 = *(const bf16x8*)&Kl[buf][l31*128 + ub];
        bf16x8 kf1 = *(const bf16x8*)&Kl[buf][(32+l31)*128 + ub];
        s0 = mfma32(kf0, qf[ks], s0);
        s1 = mfma32(kf1, qf[ks], s1);
      }
      int qabs = TC + qw0 + l31;
      if(j0 + 63 > TC + qw0){
#pragma unroll
        for(int r=0;r<16;r++){
          int kk = (r&3) + 8*(r>>2) + 4*hi;
          if(j0 + kk > qabs)      s0[r] = -1e30f;
          if(j0 + 32 + kk > qabs) s1[r] = -1e30f;
        }
      }
      float tm = fmaxf(s0[0], s1[0]);
#pragma unroll
      for(int r=1;r<16;r++) tm = fmaxf(tm, fmaxf(s0[r], s1[r]));
      tm = fmaxf(tm, __shfl_xor(tm, 32, 64));
      if(!__all(tm - m <= 8.f)){
        float mn = fmaxf(m, tm);
        float alpha = __expf(m - mn);
        m = mn;
        l *= alpha;
        float ar[16];
#pragma unroll
        for(int r=0;r<16;r++){
          int kk = (r&3) + 8*(r>>2) + 4*hi;
          ar[r] = __shfl(alpha, kk, 64);
        }
#pragma unroll
        for(int dt=0;dt<4;dt++)
#pragma unroll
          for(int r=0;r<16;r++) o[dt][r] *= ar[r];
      }
#pragma unroll
      for(int r=0;r<16;r++){ s0[r] = __expf(s0[r] - m); s1[r] = __expf(s1[r] - m); }
      float ts = 0.f;
#pragma unroll
      for(int r=0;r<16;r++) ts += s0[r] + s1[r];
      ts += __shfl_xor(ts, 32, 64);
      l += ts;
#pragma unroll
      for(int ks16=0; ks16<4; ks16++){
        f32x16 p = (ks16 & 2) ? s1 : s0;
        int fb = (ks16 & 1) * 8;
        unsigned e0 = pk2(p[fb+0], p[fb+1]);
        unsigned e1 = pk2(p[fb+2], p[fb+3]);
        unsigned e2 = pk2(p[fb+4], p[fb+5]);
        unsigned e3 = pk2(p[fb+6], p[fb+7]);
        unsigned x0 = __shfl_xor(e0, 32, 64);
        unsigned x1 = __shfl_xor(e1, 32, 64);
        unsigned x2 = __shfl_xor(e2, 32, 64);
        unsigned x3 = __shfl_xor(e3, 32, 64);
        bf16x8 pa = mk4(hi ? x2 : e0, hi ? x3 : e1, hi ? e2 : x0, hi ? e3 : x1);
        int ub = ((ks16*2 + hi) ^ r7) << 3;
#pragma unroll
        for(int dt=0; dt<4; dt++){
          bf16x8 vf = *(const bf16x8*)&Vl[buf][(dt*32 + l31)*64 + ub];
          o[dt] = mfma32(pa, vf, o[dt]);
        }
      }
    }
    __syncthreads();
    buf ^= 1;
  }

  if(split == 0){
#pragma unroll
    for(int dt=0; dt<4; dt++)
#pragma unroll
      for(int r=0; r<16; r++){
        int q = qw0 + (r&3) + 8*(r>>2) + 4*hi;
        O0[((size_t)bh*Tt + q)*Dd + dt*32 + l31] = o[dt][r];
      }
  } else {
#pragma unroll
    for(int dt=0; dt<4; dt++)
#pragma unroll
      for(int r=0; r<16; r++){
        int q = qw0 + (r&3) + 8*(r>>2) + 4*hi;
        O1b[((size_t)bh*Tt + q)*Dd + dt*32 + l31] = f2bf(o[dt][r]);
      }
  }
  if(lane < 32){
    float* mlp = ml + (((size_t)split*32 + bh)*Tt + qw0 + l31)*2;
    mlp[0] = m; mlp[1] = l;
  }
}

// ---- combine split partials -> bf16 attn_ws (MODE-0 swizzle, stride LDP) ----
__global__ __launch_bounds__(256) void combine_k(
    const float* __restrict__ O0, const unsigned short* __restrict__ O1b,
    const float* __restrict__ ml, unsigned short* __restrict__ attn_ws){
  int tid = threadIdx.x;
  int d = tid & 127, rl = tid >> 7;
  int row = blockIdx.x * 2 + rl;          // bh*1024 + t
  int bh = row >> 10, t = row & 1023;
  const float* p0 = ml + ((size_t)bh * Tt + t) * 2;
  const float* p1 = ml + (((size_t)32 + bh) * Tt + t) * 2;
  float m0 = p0[0], l0 = p0[1], m1 = p1[0], l1 = p1[1];
  float M = fmaxf(m0, m1);
  float e0 = __expf(m0 - M), e1 = __expf(m1 - M);
  float inv = 1.f / (l0*e0 + l1*e1);
  size_t off = (size_t)row * Dd + d;
  float v = (O0[off]*e0 + bf2f(O1b[off])*e1) * inv;
  int b = bh >> 4, h = bh & 15;
  int mrow = b * Tt + t;
  int c = h * Dd + d;
  int cp = (c & ~24) | ((((c>>3)&3) ^ ((mrow>>1)&3)) << 3);
  attn_ws[(size_t)mrow * LDP + cp] = f2bf(v);
}

extern "C" void kernel_launch(void* const* d_in, const int* in_sizes, int n_in,
                              void* d_out, int out_size, void* d_ws, size_t ws_size,
                              hipStream_t stream){
  const float* x       = (const float*)d_in[0];
  const float* cache_k = (const float*)d_in[1];
  const float* cache_v = (const float*)d_in[2];
  const float* W_qkv   = (const float*)d_in[3];
  const float* W_proj  = (const float*)d_in[4];
  const float* b_proj  = (const float*)d_in[5];

  float* out   = (float*)d_out;
  float* out_k = out   + (size_t)Bb*Tt*Cc;
  float* out_v = out_k + (size_t)Bb*Hh*CTX*Dd;

  if(ws_size < (size_t)67108864) return;  // need 64 MiB scratch
  char* ws = (char*)d_ws;
  // liveness-packed layout (timeline: pre, gemm8, mid, attn, combine, gemmp)
  unsigned short* WqkvT  = (unsigned short*)(ws);              // [0,25952256) 6144x2112
  unsigned short* Vt_ws  = (unsigned short*)(ws);              // [0,17039360) after gemm8
  unsigned short* attn_ws= (unsigned short*)(ws);              // [0,8650752) after attn
  unsigned short* WprojT = (unsigned short*)(ws + 17039360);   // [17039360,25690112)
  unsigned short* Kws    = (unsigned short*)(ws + 25952256);   // [25952256,42729472)
  unsigned short* q_ws   = (unsigned short*)(ws + 42729472);   // [42729472,51118080)
  unsigned short* x_bf   = (unsigned short*)(ws + 51118080);   // [51118080,59768832)
  unsigned short* O1b    = (unsigned short*)(ws + 51118080);   // after gemm8 (attn out)
  float*          ml     = (float*)(ws + 59768832);            // [59768832,60293120)
  float*          O0     = out;                                // out slot as scratch

  fused_pre_k<<<dim3(20480), 256, 0, stream>>>(
      W_qkv, WqkvT, (const float4*)x, x_bf,
      (const float4*)cache_k, (const float4*)cache_v,
      (float4*)out_k, (float4*)out_v, Kws);
  gemm8_k<<<dim3(192), 512, 0, stream>>>(x_bf, WqkvT, q_ws, out_k, out_v, Kws);
  fused_mid_k<<<dim3(12288), 256, 0, stream>>>(out_v, Vt_ws, W_proj, WprojT);
  attn_k<<<dim3(8,2,32), 256, 0, stream>>>(q_ws, Kws, Vt_ws, O0, O1b, ml);
  combine_k<<<dim3(16384), 256, 0, stream>>>(O0, O1b, ml, attn_ws);
  gemmp_k<<<dim3(16,16), 256, 0, stream>>>(attn_ws, WprojT, b_proj, out);
}

// Round 8
// 200.296 us; speedup vs baseline: 1.5537x; 1.0004x over previous
//
#include <hip/hip_runtime.h>
#include <hip/hip_bf16.h>

typedef __attribute__((ext_vector_type(8))) short bf16x8;
typedef __attribute__((ext_vector_type(4))) float f32x4;
typedef __attribute__((ext_vector_type(16))) float f32x16;

#define DI __device__ __forceinline__

static constexpr int Bb  = 2;
static constexpr int Tt  = 1024;
static constexpr int Cc  = 2048;
static constexpr int Hh  = 16;
static constexpr int Dd  = 128;
static constexpr int TC  = 1024;   // cached tokens (seq_start)
static constexpr int CTX = 2048;   // total context
static constexpr int LDP = 2112;   // padded row stride for GEMM operands
static constexpr int VS  = 2080;   // padded Vt row stride
static constexpr float QSCALE = 0.08838834764831845f; // 1/sqrt(128)

DI unsigned short f2bf(float f){
  unsigned u = __builtin_bit_cast(unsigned, f);
  u += 0x7FFFu + ((u >> 16) & 1u);
  return (unsigned short)(u >> 16);
}
DI float bf2f(unsigned short s){
  return __builtin_bit_cast(float, (unsigned)s << 16);
}
DI unsigned pk2(float a, float b){
  return (unsigned)f2bf(a) | ((unsigned)f2bf(b) << 16);
}
DI bf16x8 mk4(unsigned a, unsigned b, unsigned c, unsigned d){
  union{ unsigned u[4]; bf16x8 v; } x;
  x.u[0]=a; x.u[1]=b; x.u[2]=c; x.u[3]=d; return x.v;
}
DI f32x16 mfma32(bf16x8 a, bf16x8 b, f32x16 c){
  return __builtin_amdgcn_mfma_f32_32x32x16_bf16(a, b, c, 0, 0, 0);
}
#define MFMA16(a,b,c) __builtin_amdgcn_mfma_f32_16x16x32_bf16(a,b,c,0,0,0)
DI void gld16(const void* g, void* l){
  __builtin_amdgcn_global_load_lds(
      (const __attribute__((address_space(1))) unsigned int*)g,
      (__attribute__((address_space(3))) unsigned int*)l, 16, 0, 0);
}
DI unsigned ldsoff(const void* p){
  return (unsigned)(size_t)(const __attribute__((address_space(3))) void*)p;
}
// inline-asm LDS read: compiler-invisible (manual lgkmcnt + sched_barrier required)
template<int OFF>
DI bf16x8 dsr(unsigned addr){
  bf16x8 v;
  if constexpr (OFF == 0)
    asm volatile("ds_read_b128 %0, %1" : "=v"(v) : "v"(addr));
  else
    asm volatile("ds_read_b128 %0, %1 offset:%2" : "=v"(v) : "v"(addr), "i"(OFF));
  return v;
}
// NO-CLOBBER fences: invisible to the waitcnt pass (no mayLoad/mayStore),
// so no implicit vmcnt(0) drain of in-flight LDS-DMA is inserted around them.
#define BARNC   asm volatile("s_barrier")
#define LGKM0   asm volatile("s_waitcnt lgkmcnt(0)")
#define VMCNT4  asm volatile("s_waitcnt vmcnt(4)")
#define VMCNT0  asm volatile("s_waitcnt vmcnt(0)")
#define SBAR    __builtin_amdgcn_sched_barrier(0)

// ---- shared transpose body: fp32 [R][C] -> bf16 [C][ostride] swizzled ----
DI void transpose_body(const float* in, unsigned short* out,
                       int R, int C, int ostride, int r0, int c0, int mode,
                       unsigned short (*tile)[33]){
  int tx = threadIdx.x & 31, ty = threadIdx.x >> 5;
#pragma unroll
  for(int i=0;i<4;i++){
    int r = r0 + ty + i*8;
    tile[ty + i*8][tx] = f2bf(in[(size_t)r * C + c0 + tx]);
  }
  __syncthreads();
#pragma unroll
  for(int i=0;i<4;i++){
    int c = c0 + ty + i*8;     // out row
    int k = r0 + tx;           // out col (logical)
    int kp;
    if(mode == 0)
      kp = (k & ~24) | ((((k>>3)&3) ^ ((c>>1)&3)) << 3);
    else
      kp = (k & ~56) | ((((k>>3)&7) ^ (c&7)) << 3);
    out[(size_t)c * ostride + kp] = tile[tx][ty + i*8];
  }
}

// ---- fused pre-work: W_qkv transpose + x conv + cache copy ----
__global__ __launch_bounds__(256) void fused_pre_k(
    const float* __restrict__ W_qkv, unsigned short* __restrict__ WqkvT,
    const float4* __restrict__ x4, unsigned short* __restrict__ xbf,
    const float4* __restrict__ ck, const float4* __restrict__ cv,
    float4* __restrict__ ok, float4* __restrict__ ov,
    unsigned short* __restrict__ Kws){
  __shared__ unsigned short tile[32][33];
  int bid = blockIdx.x;
  if(bid < 12288){
    int bx = bid % 192, by = bid / 192;
    transpose_body(W_qkv, WqkvT, 2048, 6144, LDP, by*32, bx*32, 1, tile);
  } else if(bid < 16384){
    int idx = (bid - 12288) * 256 + threadIdx.x;   // x: 2048*2048/4
    int m = idx >> 9;
    int c4 = (idx & 511) * 4;
    float4 v = x4[idx];
    int cp = ((((c4>>3) ^ (m&7)) << 3)) | (c4 & 7);
    uint2 p; p.x = pk2(v.x, v.y); p.y = pk2(v.z, v.w);
    *(uint2*)(xbf + (size_t)m * LDP + cp) = p;
  } else {
    int idx = (bid - 16384) * 256 + threadIdx.x;
    const int per = TC * Dd / 4;                 // 32768 per (b,h)
    int bh = idx / per, r = idx - bh * per;
    int dst = bh * (CTX * Dd / 4) + r;
    float4 kv = ck[idx];
    ok[dst] = kv;
    ov[dst] = cv[idx];
    int key = r >> 5, dq = (r & 31) * 4;
    int dp = (((dq>>3) ^ (key&7)) << 3) | (dq & 7);
    uint2 p; p.x = pk2(kv.x, kv.y); p.y = pk2(kv.z, kv.w);
    *(uint2*)(Kws + ((size_t)bh * CTX + key) * Dd + dp) = p;
  }
}

// ---- fused mid-work: V^T (per bh) + W_proj^T ----
__global__ __launch_bounds__(256) void fused_mid_k(
    const float* __restrict__ out_v, unsigned short* __restrict__ Vt_ws,
    const float* __restrict__ W_proj, unsigned short* __restrict__ WprojT){
  __shared__ unsigned short tile[32][33];
  int bid = blockIdx.x;
  if(bid < 8192){
    int z = bid >> 8, rem = bid & 255;
    int bx = rem & 3, by = rem >> 2;
    transpose_body(out_v + (size_t)z*2048*128, Vt_ws + (size_t)z*128*VS,
                   2048, 128, VS, by*32, bx*32, 1, tile);
  } else {
    int b2 = bid - 8192;
    int bx = b2 & 63, by = b2 >> 6;
    transpose_body(W_proj, WprojT, 2048, 2048, LDP, by*32, bx*32, 0, tile);
  }
}

// ================= 128x128 BK=64 8-phase GEMM (QKV) =================
// C[m][n] = sum_k A[m][k]*W[k][n]; A, BT bf16 with u^=(row&7) unit swizzle, stride LDP.
// M=2048 N=6144 K=2048. Grid 768 (16 m x 48 n), 256 threads, 64 KiB LDS -> 2 blocks/CU.
__global__ __launch_bounds__(256, 2) void gemm8_k(
    const unsigned short* __restrict__ A, const unsigned short* __restrict__ BT,
    unsigned short* __restrict__ q_ws, float* __restrict__ out_k,
    float* __restrict__ out_v, unsigned short* __restrict__ Kws){
  __shared__ unsigned short lds[32768];        // A: [0,16384) B: [16384,32768) elems
  int tid = threadIdx.x, lane = tid & 63, w = tid >> 6;
  int lr = lane & 15, lg = lane >> 4;
  int wm = w >> 1, wn = w & 1;
  int bid = blockIdx.x;                        // 768 blocks, 768%8==0
  int swz = (bid & 7) * 96 + (bid >> 3);       // bijective XCD swizzle
  int m0 = (swz & 15) * 128;
  int n0 = (swz >> 4) * 128;

  int r8 = lane >> 3, c8 = (lane & 7) * 8;
  const unsigned short* Asrc = A  + (size_t)(m0 + w*16 + r8)*LDP + c8;
  const unsigned short* Bsrc = BT + (size_t)(n0 + w*16 + r8)*LDP + c8;
  unsigned short* ldsA = lds;
  unsigned short* ldsB = lds + 16384;

  auto stgA = [&](int b, int h, int kt){
    const unsigned short* s = Asrc + (size_t)(h*64)*LDP + kt*64;
    unsigned short* d = ldsA + b*8192 + h*4096 + w*1024;
    gld16(s, d);
    gld16(s + (size_t)8*LDP, d + 512);
  };
  auto stgB = [&](int b, int h, int kt){
    const unsigned short* s = Bsrc + (size_t)(h*64)*LDP + kt*64;
    unsigned short* d = ldsB + b*8192 + h*4096 + w*1024;
    gld16(s, d);
    gld16(s + (size_t)8*LDP, d + 512);
  };

  // byte addresses for asm ds_read (row stride 128 B, buffer stride 16384 B)
  unsigned LB   = ldsoff(lds);
  unsigned apAb = LB + (unsigned)(wm*64 + lr)*128;             // A row base (bytes)
  unsigned apBb = LB + 32768u + (unsigned)(wn*64 + lr)*128;    // B row base (bytes)
  unsigned ua0b = (unsigned)(( lg      ^ (lr & 7)) * 16);      // kk=0 unit (bytes)
  unsigned ua1b = (unsigned)(((4 + lg) ^ (lr & 7)) * 16);      // kk=1 unit (bytes)

  f32x4 acc[4][4];
#pragma unroll
  for(int i=0;i<4;i++)
#pragma unroll
    for(int j=0;j<4;j++) acc[i][j] = (f32x4){0.f,0.f,0.f,0.f};
  bf16x8 bfr[4][2];

  // prologue: K-tile0 fully + B(1); leave B(1) in flight
  stgA(0,0,0); stgA(0,1,0); stgB(0,0,0); stgB(0,1,0); stgB(1,0,1); stgB(1,1,1);
  SBAR;
  VMCNT4;
  BARNC;

#define PHASE(BUF, Q, STAGE, VM)                                           \
  {                                                                        \
    unsigned a0 = apAb + (BUF)*16384u + (Q)*2048u + ua0b;                  \
    unsigned a1 = apAb + (BUF)*16384u + (Q)*2048u + ua1b;                  \
    bf16x8 a00 = dsr<0>(a0);                                               \
    bf16x8 a01 = dsr<0>(a1);                                               \
    if((Q) == 0){                                                          \
      unsigned b0 = apBb + (BUF)*16384u + ua0b;                            \
      unsigned b1 = apBb + (BUF)*16384u + ua1b;                            \
      bfr[0][0] = dsr<0>(b0);    bfr[1][0] = dsr<2048>(b0);                \
      bfr[2][0] = dsr<4096>(b0); bfr[3][0] = dsr<6144>(b0);                \
      bfr[0][1] = dsr<0>(b1);    bfr[1][1] = dsr<2048>(b1);                \
      bfr[2][1] = dsr<4096>(b1); bfr[3][1] = dsr<6144>(b1);                \
    }                                                                      \
    SBAR;                                                                  \
    STAGE;                                                                 \
    SBAR;                                                                  \
    BARNC;                                                                 \
    LGKM0;                                                                 \
    SBAR;                                                                  \
    __builtin_amdgcn_s_setprio(1);                                         \
    _Pragma("unroll")                                                      \
    for(int ni=0;ni<4;ni++)                                                \
      acc[(Q)][ni] = MFMA16(a00, bfr[ni][0], acc[(Q)][ni]);                \
    _Pragma("unroll")                                                      \
    for(int ni=0;ni<4;ni++)                                                \
      acc[(Q)][ni] = MFMA16(a01, bfr[ni][1], acc[(Q)][ni]);                \
    __builtin_amdgcn_s_setprio(0);                                         \
    SBAR;                                                                  \
    VM;                                                                    \
    BARNC;                                                                 \
  }

#pragma unroll 1
  for(int i=0;i<16;i++){
    int t1 = 2*i+1, t2 = (2*i+2)&31, t3 = (2*i+3)&31;
    PHASE(0, 0, stgA(1,0,t1), );
    PHASE(0, 1, stgA(1,1,t1), );
    PHASE(0, 2, stgB(0,0,t2), );
    PHASE(0, 3, stgB(0,1,t2), VMCNT4);
    PHASE(1, 0, stgA(0,0,t2), );
    PHASE(1, 1, stgA(0,1,t2), );
    PHASE(1, 2, stgB(1,0,t3), );
    PHASE(1, 3, stgB(1,1,t3), VMCNT4);
  }
#undef PHASE
  asm volatile("s_waitcnt vmcnt(0)" ::: "memory");

  // epilogue: QKV scatter
#pragma unroll
  for(int mi=0;mi<4;mi++){
#pragma unroll
    for(int ni=0;ni<4;ni++){
      int n = n0 + wn*64 + ni*16 + lr;
      int seg = n >> 11;
      int h = (n >> 7) & 15, d = n & 127;
#pragma unroll
      for(int r=0;r<4;r++){
        int mrow = m0 + wm*64 + mi*16 + lg*4 + r;
        float v = acc[mi][ni][r];
        int b = mrow >> 10, t = mrow & 1023;
        if(seg == 0){
          q_ws[((size_t)(b*Hh + h)*Tt + t)*Dd + d] = f2bf(v * QSCALE);
        } else if(seg == 1){
          int key = TC + t;
          size_t base = (size_t)(b*Hh + h)*CTX + key;
          out_k[base*Dd + d] = v;
          int dp = (((d>>3) ^ (key&7)) << 3) | (d & 7);
          Kws[base*Dd + dp] = f2bf(v);
        } else {
          out_v[((size_t)(b*Hh + h)*CTX + TC + t)*Dd + d] = v;
        }
      }
    }
  }
}

// ---- 128x128 BK=32 GEMM (proj): counted-vmcnt + no-clobber fences ----
__global__ __launch_bounds__(256) void gemmp_k(
    const unsigned short* __restrict__ A, const unsigned short* __restrict__ BT,
    const float* __restrict__ bias, float* __restrict__ outp){
  constexpr int K = 2048;
  __shared__ unsigned short Al[2][128*32];
  __shared__ unsigned short Bl[2][128*32];
  int tid = threadIdx.x, lane = tid & 63, w = tid >> 6;
  int lr = lane & 15, lg = lane >> 4;
  int m0 = blockIdx.x * 128, n0 = blockIdx.y * 128;
  int wr = (w >> 1) * 64, wc = (w & 1) * 64;
  int swz = (lg ^ ((lr >> 1) & 3)) << 3;

  unsigned baseAb = ldsoff(Al) + (unsigned)(((wr + lr)*32 + swz)*2);
  unsigned baseBb = ldsoff(Bl) + (unsigned)(((wc + lr)*32 + swz)*2);

  f32x4 acc[4][4];
#pragma unroll
  for(int i=0;i<4;i++)
#pragma unroll
    for(int j=0;j<4;j++) acc[i][j] = (f32x4){0.f,0.f,0.f,0.f};

  auto stage = [&](int buf, int k0){
#pragma unroll
    for(int li=0; li<2; li++){
      int rb = w*32 + li*16;
      gld16(A  + (size_t)(m0 + rb + (lane>>2))*LDP + k0 + (lane&3)*8, &Al[buf][rb*32]);
      gld16(BT + (size_t)(n0 + rb + (lane>>2))*LDP + k0 + (lane&3)*8, &Bl[buf][rb*32]);
    }
  };
  stage(0, 0);                      // 4 loads in flight
  int buf = 0;
#pragma unroll 1
  for(int k0 = 0; k0 < K; k0 += 32){
    SBAR;
    if(k0 + 32 < K){
      stage(buf^1, k0 + 32);        // +4 -> 8 in flight
      SBAR;
      VMCNT4;                       // buf's 4 landed; next-buf 4 stay in flight
    } else {
      SBAR;
      VMCNT0;
    }
    BARNC;                          // all waves' buf loads landed
    unsigned aA = baseAb + (unsigned)buf*8192u;
    unsigned aB = baseBb + (unsigned)buf*8192u;
    bf16x8 af[4], bfr[4];
    af[0]  = dsr<0>(aA);    af[1]  = dsr<1024>(aA);
    af[2]  = dsr<2048>(aA); af[3]  = dsr<3072>(aA);
    bfr[0] = dsr<0>(aB);    bfr[1] = dsr<1024>(aB);
    bfr[2] = dsr<2048>(aB); bfr[3] = dsr<3072>(aB);
    LGKM0;
    SBAR;
    __builtin_amdgcn_s_setprio(1);
#pragma unroll
    for(int mi=0;mi<4;mi++)
#pragma unroll
      for(int ni=0;ni<4;ni++)
        acc[mi][ni] = MFMA16(af[mi], bfr[ni], acc[mi][ni]);
    __builtin_amdgcn_s_setprio(0);
    SBAR;
    BARNC;                          // reads done before next iter overwrites buf
    buf ^= 1;
  }

#pragma unroll
  for(int mi=0;mi<4;mi++){
#pragma unroll
    for(int ni=0;ni<4;ni++){
      int n = n0 + wc + ni*16 + lr;
#pragma unroll
      for(int r=0;r<4;r++){
        int mrow = m0 + wr + mi*16 + lg*4 + r;
        outp[(size_t)mrow * Cc + n] = acc[mi][ni][r] + bias[n];
      }
    }
  }
}

// ---- flash attention, swapped-QK 32x32, 4 waves x 32q, key-split x2 ----
__global__ __launch_bounds__(256, 2) void attn_k(
    const unsigned short* __restrict__ q_ws,
    const unsigned short* __restrict__ Kws,
    const unsigned short* __restrict__ Vt,
    float* __restrict__ O0, unsigned short* __restrict__ O1b,
    float* __restrict__ ml){
  __shared__ unsigned short Kl[2][64*128];   // [key][128] swizzled
  __shared__ unsigned short Vl[2][128*64];   // [d][64]  swizzled
  int tid = threadIdx.x, lane = tid & 63, w = tid >> 6;
  int l31 = lane & 31, hi = lane >> 5, r7 = l31 & 7;
  int qt = blockIdx.x, split = blockIdx.y, bh = blockIdx.z;
  int q0b = qt * 128, qw0 = q0b + w * 32;
  const unsigned short* Kb = Kws + (size_t)bh * CTX * Dd;
  const unsigned short* Vb = Vt  + (size_t)bh * Dd * VS;

  const unsigned short* qp = q_ws + ((size_t)bh * Tt + qw0 + l31) * Dd + hi * 8;
  bf16x8 qf[8];
#pragma unroll
  for(int ks=0;ks<8;ks++) qf[ks] = *(const bf16x8*)(qp + ks*16);

  f32x16 o[4];
#pragma unroll
  for(int dt=0;dt<4;dt++)
#pragma unroll
    for(int r=0;r<16;r++) o[dt][r] = 0.f;
  float m = -3e38f, l = 0.f;

  int nts = ((TC + q0b + 128) >> 6) >> 1;   // tiles for this split

  auto stageK = [&](int buf, int j0){
#pragma unroll
    for(int li=0; li<4; li++){
      gld16(Kb + (size_t)(j0 + w*16 + li*4 + (lane>>4))*Dd + (lane&15)*8,
            &Kl[buf][(w*16 + li*4)*128]);
    }
  };
  auto stageV = [&](int buf, int j0){
#pragma unroll
    for(int li=0; li<4; li++){
      gld16(Vb + (size_t)(w*32 + li*8 + (lane>>3))*VS + j0 + (lane&7)*8,
            &Vl[buf][(w*32 + li*8)*64]);
    }
  };

  stageK(0, split*64); stageV(0, split*64);
  __syncthreads();
  int buf = 0;
#pragma unroll 1
  for(int t = 0; t < nts; t++){
    int j0 = (2*t + split) * 64;
    if(t + 1 < nts){ stageK(buf^1, j0 + 128); stageV(buf^1, j0 + 128); }

    if(j0 <= TC + qw0 + 31){
      f32x16 s0, s1;
#pragma unroll
      for(int r=0;r<16;r++){ s0[r] = 0.f; s1[r] = 0.f; }
#pragma unroll
      for(int ks=0; ks<8; ks++){
        int ub = ((ks*2 + hi) ^ r7) << 3;
        bf16x8 kf0 = *(const bf16x8*)&Kl[buf][l31*128 + ub];
        bf16x8 kf1 = *(const bf16x8*)&Kl[buf][(32+l31)*128 + ub];
        s0 = mfma32(kf0, qf[ks], s0);
        s1 = mfma32(kf1, qf[ks], s1);
      }
      int qabs = TC + qw0 + l31;
      if(j0 + 63 > TC + qw0){
#pragma unroll
        for(int r=0;r<16;r++){
          int kk = (r&3) + 8*(r>>2) + 4*hi;
          if(j0 + kk > qabs)      s0[r] = -1e30f;
          if(j0 + 32 + kk > qabs) s1[r] = -1e30f;
        }
      }
      float tm = fmaxf(s0[0], s1[0]);
#pragma unroll
      for(int r=1;r<16;r++) tm = fmaxf(tm, fmaxf(s0[r], s1[r]));
      tm = fmaxf(tm, __shfl_xor(tm, 32, 64));
      if(!__all(tm - m <= 8.f)){
        float mn = fmaxf(m, tm);
        float alpha = __expf(m - mn);
        m = mn;
        l *= alpha;
        float ar[16];
#pragma unroll
        for(int r=0;r<16;r++){
          int kk = (r&3) + 8*(r>>2) + 4*hi;
          ar[r] = __shfl(alpha, kk, 64);
        }
#pragma unroll
        for(int dt=0;dt<4;dt++)
#pragma unroll
          for(int r=0;r<16;r++) o[dt][r] *= ar[r];
      }
#pragma unroll
      for(int r=0;r<16;r++){ s0[r] = __expf(s0[r] - m); s1[r] = __expf(s1[r] - m); }
      float ts = 0.f;
#pragma unroll
      for(int r=0;r<16;r++) ts += s0[r] + s1[r];
      ts += __shfl_xor(ts, 32, 64);
      l += ts;
#pragma unroll
      for(int ks16=0; ks16<4; ks16++){
        f32x16 p = (ks16 & 2) ? s1 : s0;
        int fb = (ks16 & 1) * 8;
        unsigned e0 = pk2(p[fb+0], p[fb+1]);
        unsigned e1 = pk2(p[fb+2], p[fb+3]);
        unsigned e2 = pk2(p[fb+4], p[fb+5]);
        unsigned e3 = pk2(p[fb+6], p[fb+7]);
        unsigned x0 = __shfl_xor(e0, 32, 64);
        unsigned x1 = __shfl_xor(e1, 32, 64);
        unsigned x2 = __shfl_xor(e2, 32, 64);
        unsigned x3 = __shfl_xor(e3, 32, 64);
        bf16x8 pa = mk4(hi ? x2 : e0, hi ? x3 : e1, hi ? e2 : x0, hi ? e3 : x1);
        int ub = ((ks16*2 + hi) ^ r7) << 3;
#pragma unroll
        for(int dt=0; dt<4; dt++){
          bf16x8 vf = *(const bf16x8*)&Vl[buf][(dt*32 + l31)*64 + ub];
          o[dt] = mfma32(pa, vf, o[dt]);
        }
      }
    }
    __syncthreads();
    buf ^= 1;
  }

  if(split == 0){
#pragma unroll
    for(int dt=0; dt<4; dt++)
#pragma unroll
      for(int r=0; r<16; r++){
        int q = qw0 + (r&3) + 8*(r>>2) + 4*hi;
        O0[((size_t)bh*Tt + q)*Dd + dt*32 + l31] = o[dt][r];
      }
  } else {
#pragma unroll
    for(int dt=0; dt<4; dt++)
#pragma unroll
      for(int r=0; r<16; r++){
        int q = qw0 + (r&3) + 8*(r>>2) + 4*hi;
        O1b[((size_t)bh*Tt + q)*Dd + dt*32 + l31] = f2bf(o[dt][r]);
      }
  }
  if(lane < 32){
    float* mlp = ml + (((size_t)split*32 + bh)*Tt + qw0 + l31)*2;
    mlp[0] = m; mlp[1] = l;
  }
}

// ---- combine split partials -> bf16 attn_ws (MODE-0 swizzle, stride LDP) ----
__global__ __launch_bounds__(256) void combine_k(
    const float* __restrict__ O0, const unsigned short* __restrict__ O1b,
    const float* __restrict__ ml, unsigned short* __restrict__ attn_ws){
  int tid = threadIdx.x;
  int d = tid & 127, rl = tid >> 7;
  int row = blockIdx.x * 2 + rl;          // bh*1024 + t
  int bh = row >> 10, t = row & 1023;
  const float* p0 = ml + ((size_t)bh * Tt + t) * 2;
  const float* p1 = ml + (((size_t)32 + bh) * Tt + t) * 2;
  float m0 = p0[0], l0 = p0[1], m1 = p1[0], l1 = p1[1];
  float M = fmaxf(m0, m1);
  float e0 = __expf(m0 - M), e1 = __expf(m1 - M);
  float inv = 1.f / (l0*e0 + l1*e1);
  size_t off = (size_t)row * Dd + d;
  float v = (O0[off]*e0 + bf2f(O1b[off])*e1) * inv;
  int b = bh >> 4, h = bh & 15;
  int mrow = b * Tt + t;
  int c = h * Dd + d;
  int cp = (c & ~24) | ((((c>>3)&3) ^ ((mrow>>1)&3)) << 3);
  attn_ws[(size_t)mrow * LDP + cp] = f2bf(v);
}

extern "C" void kernel_launch(void* const* d_in, const int* in_sizes, int n_in,
                              void* d_out, int out_size, void* d_ws, size_t ws_size,
                              hipStream_t stream){
  const float* x       = (const float*)d_in[0];
  const float* cache_k = (const float*)d_in[1];
  const float* cache_v = (const float*)d_in[2];
  const float* W_qkv   = (const float*)d_in[3];
  const float* W_proj  = (const float*)d_in[4];
  const float* b_proj  = (const float*)d_in[5];

  float* out   = (float*)d_out;
  float* out_k = out   + (size_t)Bb*Tt*Cc;
  float* out_v = out_k + (size_t)Bb*Hh*CTX*Dd;

  if(ws_size < (size_t)67108864) return;  // need 64 MiB scratch
  char* ws = (char*)d_ws;
  // liveness-packed layout (timeline: pre, gemm8, mid, attn, combine, gemmp)
  unsigned short* WqkvT  = (unsigned short*)(ws);              // [0,25952256) 6144x2112
  unsigned short* Vt_ws  = (unsigned short*)(ws);              // [0,17039360) after gemm8
  unsigned short* attn_ws= (unsigned short*)(ws);              // [0,8650752) after attn
  unsigned short* WprojT = (unsigned short*)(ws + 17039360);   // [17039360,25690112)
  unsigned short* Kws    = (unsigned short*)(ws + 25952256);   // [25952256,42729472)
  unsigned short* q_ws   = (unsigned short*)(ws + 42729472);   // [42729472,51118080)
  unsigned short* x_bf   = (unsigned short*)(ws + 51118080);   // [51118080,59768832)
  unsigned short* O1b    = (unsigned short*)(ws + 51118080);   // after gemm8 (attn out)
  float*          ml     = (float*)(ws + 59768832);            // [59768832,60293120)
  float*          O0     = out;                                // out slot as scratch

  fused_pre_k<<<dim3(20480), 256, 0, stream>>>(
      W_qkv, WqkvT, (const float4*)x, x_bf,
      (const float4*)cache_k, (const float4*)cache_v,
      (float4*)out_k, (float4*)out_v, Kws);
  gemm8_k<<<dim3(768), 256, 0, stream>>>(x_bf, WqkvT, q_ws, out_k, out_v, Kws);
  fused_mid_k<<<dim3(12288), 256, 0, stream>>>(out_v, Vt_ws, W_proj, WprojT);
  attn_k<<<dim3(8,2,32), 256, 0, stream>>>(q_ws, Kws, Vt_ws, O0, O1b, ml);
  combine_k<<<dim3(16384), 256, 0, stream>>>(O0, O1b, ml, attn_ws);
  gemmp_k<<<dim3(16,16), 256, 0, stream>>>(attn_ws, WprojT, b_proj, out);
}